// Round 9
// baseline (3135.851 us; speedup 1.0000x reference)
//
#include <hip/hip_runtime.h>
#include <hip/hip_bf16.h>

#define N_NODES 50000
#define N_EDGES 600000
#define N_GRAPHS 64

typedef __hip_bfloat16 bf16;
typedef __attribute__((ext_vector_type(8))) short short8;
typedef __attribute__((ext_vector_type(4))) float f32x4;

static __device__ inline short bfbits(float x) {
  union { bf16 h; short s; } u;
  u.h = __float2bfloat16(x);
  return u.s;
}
static __device__ inline float bfu(unsigned short s) {
  union { float f; unsigned u; } x; x.u = ((unsigned)s) << 16; return x.f;
}
static __device__ inline short8 cvt8(const float* p) {
  f32x4 v0 = *(const f32x4*)p, v1 = *(const f32x4*)(p + 4);
  short8 r;
  r[0] = bfbits(v0[0]); r[1] = bfbits(v0[1]); r[2] = bfbits(v0[2]); r[3] = bfbits(v0[3]);
  r[4] = bfbits(v1[0]); r[5] = bfbits(v1[1]); r[6] = bfbits(v1[2]); r[7] = bfbits(v1[3]);
  return r;
}

// float dtype detection: bf16 (flag=0) or float32 (flag=1)?  (R5 verified: f32)
__global__ void detect_f_kernel(const unsigned short* __restrict__ raw, int* __restrict__ flag) {
  int t = threadIdx.x;  // 64 threads
  int wild = 0;
  for (int i = 0; i < 4; ++i) {
    unsigned short u = raw[t * 4 + i];
    int e = (u >> 7) & 0xFF;
    if (u != 0 && (e < 96 || e > 159)) wild++;
  }
#pragma unroll
  for (int off = 32; off > 0; off >>= 1) wild += __shfl_down(wild, off);
  if (t == 0) *flag = (wild >= 32) ? 1 : 0;
}

__global__ void cvt_kernel(const void* __restrict__ src, float* __restrict__ dst, int n,
                           const int* __restrict__ flag) {
  int i = blockIdx.x * 256 + threadIdx.x;
  if (i >= n) return;
  if (*flag) dst[i] = ((const float*)src)[i];
  else dst[i] = bfu(((const unsigned short*)src)[i]);
}

// Pack B[k][n] (K x NN) into MFMA 16x16x32 b-frag order from canonical f32.
__global__ void pack_b_kernel(const float* __restrict__ src, bf16* __restrict__ dst,
                              int K, int NN, int transpose) {
  int tid = blockIdx.x * 256 + threadIdx.x;
  if (tid >= K * NN) return;
  int NT = NN >> 4;
  int i = tid & 7;
  int lane = (tid >> 3) & 63;
  int rest = tid >> 9;
  int nt = rest % NT;
  int kt = rest / NT;
  int k = kt * 32 + ((lane >> 4) << 3) + i;
  int n = nt * 16 + (lane & 15);
  dst[tid] = __float2bfloat16(transpose ? src[n * K + k] : src[k * NN + n]);
}

__global__ void embed_kernel(const int* __restrict__ idx, const void* __restrict__ emb_raw,
                             bf16* __restrict__ feat, const int* __restrict__ flag) {
  int tid = blockIdx.x * 256 + threadIdx.x;  // exactly N_NODES*128
  int n = tid >> 7, h = tid & 127;
  float v;
  if (*flag) v = ((const float*)emb_raw)[(size_t)idx[n] * 128 + h];
  else       v = bfu(((const unsigned short*)emb_raw)[(size_t)idx[n] * 128 + h]);
  feat[tid] = __float2bfloat16(v);
}

__global__ void count_kernel(const int* __restrict__ gid, float* __restrict__ cnt) {
  int n = blockIdx.x * 256 + threadIdx.x;
  if (n < N_NODES) atomicAdd(&cnt[gid[n]], 1.0f);
}

__global__ void mean_atomic_kernel(const bf16* __restrict__ feat, const int* __restrict__ gid,
                                   float* __restrict__ gsum, int slot) {
  int tid = blockIdx.x * 256 + threadIdx.x;  // exactly N_NODES*128
  int n = tid >> 7, h = tid & 127;
  atomicAdd(&gsum[gid[n] * 384 + slot * 128 + h], __bfloat162float(feat[tid]));
}

// Wh1[n][128] = bf16( feat @ W_t + b_t )  for ONE etype
__launch_bounds__(256)
__global__ void gemm_wh1_kernel(const bf16* __restrict__ A, const bf16* __restrict__ Bp,
                                const float* __restrict__ bias, bf16* __restrict__ C) {
  const int lane = threadIdx.x & 63;
  const int w = threadIdx.x >> 6;
  const int r0 = blockIdx.x * 64 + w * 16;
  int arow = r0 + (lane & 15);
  if (arow >= N_NODES) arow = N_NODES - 1;
  const int kb = (lane >> 4) << 3;
  short8 af[4];
#pragma unroll
  for (int kt = 0; kt < 4; ++kt)
    af[kt] = *(const short8*)(A + (size_t)arow * 128 + kt * 32 + kb);
  const int crow0 = r0 + ((lane >> 4) << 2);
  const int ccol = lane & 15;
#pragma unroll
  for (int nt = 0; nt < 8; ++nt) {
    f32x4 acc = {0.f, 0.f, 0.f, 0.f};
#pragma unroll
    for (int kt = 0; kt < 4; ++kt) {
      short8 bfr = *(const short8*)(Bp + ((kt * 8 + nt) * 64 + lane) * 8);
      acc = __builtin_amdgcn_mfma_f32_16x16x32_bf16(af[kt], bfr, acc, 0, 0, 0);
    }
    float bv = bias[nt * 16 + ccol];
#pragma unroll
    for (int rr = 0; rr < 4; ++rr) {
      int row = crow0 + rr;
      if (row < N_NODES) C[(size_t)row * 128 + nt * 16 + ccol] = __float2bfloat16(acc[rr] + bv);
    }
  }
}

// a[dst] += Wh1[src]  for edges with etype == pass
__global__ void edge_kernel(const int* __restrict__ src, const int* __restrict__ dst,
                            const int* __restrict__ et, const bf16* __restrict__ Wh,
                            float* __restrict__ a, int pass) {
  int e = blockIdx.x * 4 + (threadIdx.x >> 6);
  if (et[e] != pass) return;
  int lane = threadIdx.x & 63;
  int s = src[e], d = dst[e];
  unsigned u = *(const unsigned*)(Wh + (size_t)s * 128 + lane * 2);
  atomicAdd(&a[(size_t)d * 128 + lane * 2],     bfu((unsigned short)(u & 0xffff)));
  atomicAdd(&a[(size_t)d * 128 + lane * 2 + 1], bfu((unsigned short)(u >> 16)));
}

// Fused: gi = a@Wih^T+bih, gh = feat@Whh^T+bhh, GRU gate, feat(bf16) update in place.
__launch_bounds__(256)
__global__ void gru_kernel(const float* __restrict__ a, bf16* __restrict__ feat,
                           const bf16* __restrict__ Bih, const bf16* __restrict__ Bhh,
                           const float* __restrict__ bih, const float* __restrict__ bhh) {
  const int lane = threadIdx.x & 63;
  const int w = threadIdx.x >> 6;
  const int r0 = blockIdx.x * 64 + w * 16;
  int arow = r0 + (lane & 15);
  if (arow >= N_NODES) arow = N_NODES - 1;
  const int kb = (lane >> 4) << 3;
  short8 fa[4], fh[4];
#pragma unroll
  for (int kt = 0; kt < 4; ++kt) {
    fa[kt] = cvt8(a + (size_t)arow * 128 + kt * 32 + kb);
    fh[kt] = *(const short8*)(feat + (size_t)arow * 128 + kt * 32 + kb);
  }
  const int crow0 = r0 + ((lane >> 4) << 2);
  const int ccol = lane & 15;
  f32x4 rg[8], zg[8];
#pragma unroll
  for (int g = 0; g < 3; ++g) {
#pragma unroll
    for (int nt = 0; nt < 8; ++nt) {
      const int ntg = g * 8 + nt;
      f32x4 gi = {0.f, 0.f, 0.f, 0.f}, gh = {0.f, 0.f, 0.f, 0.f};
#pragma unroll
      for (int kt = 0; kt < 4; ++kt) {
        short8 bi = *(const short8*)(Bih + ((size_t)(kt * 24 + ntg) * 64 + lane) * 8);
        short8 bh = *(const short8*)(Bhh + ((size_t)(kt * 24 + ntg) * 64 + lane) * 8);
        gi = __builtin_amdgcn_mfma_f32_16x16x32_bf16(fa[kt], bi, gi, 0, 0, 0);
        gh = __builtin_amdgcn_mfma_f32_16x16x32_bf16(fh[kt], bh, gh, 0, 0, 0);
      }
      float bvi = bih[ntg * 16 + ccol];
      float bvh = bhh[ntg * 16 + ccol];
      if (g == 0) {
#pragma unroll
        for (int rr = 0; rr < 4; ++rr)
          rg[nt][rr] = 1.f / (1.f + __expf(-(gi[rr] + bvi + gh[rr] + bvh)));
      } else if (g == 1) {
#pragma unroll
        for (int rr = 0; rr < 4; ++rr)
          zg[nt][rr] = 1.f / (1.f + __expf(-(gi[rr] + bvi + gh[rr] + bvh)));
      } else {
#pragma unroll
        for (int rr = 0; rr < 4; ++rr) {
          int row = crow0 + rr;
          if (row < N_NODES) {
            int col = nt * 16 + ccol;
            float hn = gh[rr] + bvh;
            float nc = tanhf(gi[rr] + bvi + rg[nt][rr] * hn);
            float hv = __bfloat162float(feat[(size_t)row * 128 + col]);
            float z = zg[nt][rr];
            feat[(size_t)row * 128 + col] = __float2bfloat16((1.f - z) * nc + z * hv);
          }
        }
      }
    }
  }
}

// OUTPUT IS FLOAT32 (reference returns jax f32 arrays).
__global__ void final_kernel(const float* __restrict__ gsum, const float* __restrict__ cnt,
                             const float* __restrict__ W1, const float* __restrict__ b1,
                             const float* __restrict__ W2, const float* __restrict__ b2,
                             float* __restrict__ out) {
  __shared__ float ga[384];
  __shared__ float red[2];
  int g = blockIdx.x, t = threadIdx.x;
  float c = fmaxf(cnt[g], 1.f);
  for (int k = t; k < 384; k += 128) {
    float m = gsum[g * 384 + k] / c;
    ga[k] = m;
    out[64 + g * 384 + k] = m;
  }
  __syncthreads();
  float acc = b1[t];
  for (int k = 0; k < 384; ++k) acc += ga[k] * W1[k * 128 + t];
  float x = fmaxf(acc, 0.f);
  float pv = x * W2[t];
#pragma unroll
  for (int off = 32; off > 0; off >>= 1) pv += __shfl_down(pv, off);
  if ((t & 63) == 0) red[t >> 6] = pv;
  __syncthreads();
  if (t == 0) out[g] = red[0] + red[1] + b2[0];
}

extern "C" void kernel_launch(void* const* d_in, const int* in_sizes, int n_in,
                              void* d_out, int out_size, void* d_ws, size_t ws_size,
                              hipStream_t stream) {
  const int* text_idx = (const int*)d_in[0];
  const int* srcp     = (const int*)d_in[1];
  const int* dstp     = (const int*)d_in[2];
  const int* etype    = (const int*)d_in[3];
  const int* gid      = (const int*)d_in[4];
  float* out = (float*)d_out;
  float* ws = (float*)d_ws;

  bf16*  feat = (bf16*)ws;                     // 6.4M bf16
  float* a    = ws + 3200000;                  // 6.4M f32
  bf16*  Wh1  = (bf16*)(ws + 9600000);         // 6.4M bf16
  bf16*  packWe  = (bf16*)(ws + 12800000);     // 98,304 bf16 (6 x 16384)
  bf16*  packWih = packWe + 98304;             // 98,304 bf16
  bf16*  packWhh = packWih + 98304;            // 98,304 bf16
  float* canon = ws + 12947456;
  float* cWl  = canon;                // 98,304
  float* cWih = canon + 98304;        // 98,304
  float* cWhh = canon + 196608;       // 98,304
  float* cbl  = canon + 294912;       // 768
  float* cbih = canon + 295680;       // 768
  float* cbhh = canon + 296448;       // 768
  float* cW1  = canon + 297216;       // 49,152
  float* cb1  = canon + 346368;       // 128
  float* cW2  = canon + 346496;       // 128
  float* cb2  = canon + 346624;       // 16 (pad)
  float* gsum = ws + 13294096;        // 24,576
  float* cnt  = ws + 13318672;        // 64
  int*   fflag = (int*)(ws + 13318736);
  // total ~53.3 MB (ws_size >= 54 MB verified in R5)

  detect_f_kernel<<<1, 64, 0, stream>>>((const unsigned short*)d_in[5], fflag);

  cvt_kernel<<<384, 256, 0, stream>>>(d_in[6],  cWl,  98304, fflag);
  cvt_kernel<<<3,   256, 0, stream>>>(d_in[7],  cbl,  768,   fflag);
  cvt_kernel<<<384, 256, 0, stream>>>(d_in[8],  cWih, 98304, fflag);
  cvt_kernel<<<384, 256, 0, stream>>>(d_in[9],  cWhh, 98304, fflag);
  cvt_kernel<<<3,   256, 0, stream>>>(d_in[10], cbih, 768,   fflag);
  cvt_kernel<<<3,   256, 0, stream>>>(d_in[11], cbhh, 768,   fflag);
  cvt_kernel<<<192, 256, 0, stream>>>(d_in[12], cW1,  49152, fflag);
  cvt_kernel<<<1,   256, 0, stream>>>(d_in[13], cb1,  128,   fflag);
  cvt_kernel<<<1,   256, 0, stream>>>(d_in[14], cW2,  128,   fflag);
  cvt_kernel<<<1,   256, 0, stream>>>(d_in[15], cb2,  1,     fflag);

  hipMemsetAsync(gsum, 0, (24576 + 64) * sizeof(float), stream);

  for (int m = 0; m < 6; ++m)
    pack_b_kernel<<<64, 256, 0, stream>>>(cWl + m * 16384, packWe + m * 16384, 128, 128, 0);
  for (int l = 0; l < 2; ++l) {
    pack_b_kernel<<<192, 256, 0, stream>>>(cWih + l * 49152, packWih + l * 49152, 128, 384, 1);
    pack_b_kernel<<<192, 256, 0, stream>>>(cWhh + l * 49152, packWhh + l * 49152, 128, 384, 1);
  }

  embed_kernel<<<25000, 256, 0, stream>>>(text_idx, d_in[5], feat, fflag);
  count_kernel<<<196, 256, 0, stream>>>(gid, cnt);
  mean_atomic_kernel<<<25000, 256, 0, stream>>>(feat, gid, gsum, 0);

  for (int l = 0; l < 2; ++l) {
    for (int s = 0; s < 2; ++s) {
      hipMemsetAsync(a, 0, 6400000 * sizeof(float), stream);
      for (int t = 0; t < 3; ++t) {
        gemm_wh1_kernel<<<782, 256, 0, stream>>>(feat, packWe + (l * 3 + t) * 16384,
                                                 cbl + l * 384 + t * 128, Wh1);
        edge_kernel<<<150000, 256, 0, stream>>>(srcp, dstp, etype, Wh1, a, t);
      }
      gru_kernel<<<782, 256, 0, stream>>>(a, feat, packWih + l * 49152, packWhh + l * 49152,
                                          cbih + l * 384, cbhh + l * 384);
    }
    mean_atomic_kernel<<<25000, 256, 0, stream>>>(feat, gid, gsum, l + 1);
  }

  final_kernel<<<64, 128, 0, stream>>>(gsum, cnt, cW1, cb1, cW2, cb2, out);
}

// Round 10
// 2621.879 us; speedup vs baseline: 1.1960x; 1.1960x over previous
//
#include <hip/hip_runtime.h>
#include <hip/hip_bf16.h>

#define N_NODES 50000
#define N_EDGES 600000
#define N_GRAPHS 64

typedef __hip_bfloat16 bf16;
typedef __attribute__((ext_vector_type(8))) short short8;
typedef __attribute__((ext_vector_type(4))) float f32x4;

static __device__ inline short bfbits(float x) {
  union { bf16 h; short s; } u;
  u.h = __float2bfloat16(x);
  return u.s;
}
static __device__ inline float bfu(unsigned short s) {
  union { float f; unsigned u; } x; x.u = ((unsigned)s) << 16; return x.f;
}
static __device__ inline short8 cvt8(const float* p) {
  f32x4 v0 = *(const f32x4*)p, v1 = *(const f32x4*)(p + 4);
  short8 r;
  r[0] = bfbits(v0[0]); r[1] = bfbits(v0[1]); r[2] = bfbits(v0[2]); r[3] = bfbits(v0[3]);
  r[4] = bfbits(v1[0]); r[5] = bfbits(v1[1]); r[6] = bfbits(v1[2]); r[7] = bfbits(v1[3]);
  return r;
}

// float dtype detection: bf16 (flag=0) or float32 (flag=1)?  (R5 verified: f32)
__global__ void detect_f_kernel(const unsigned short* __restrict__ raw, int* __restrict__ flag) {
  int t = threadIdx.x;  // 64 threads
  int wild = 0;
  for (int i = 0; i < 4; ++i) {
    unsigned short u = raw[t * 4 + i];
    int e = (u >> 7) & 0xFF;
    if (u != 0 && (e < 96 || e > 159)) wild++;
  }
#pragma unroll
  for (int off = 32; off > 0; off >>= 1) wild += __shfl_down(wild, off);
  if (t == 0) *flag = (wild >= 32) ? 1 : 0;
}

__global__ void cvt_kernel(const void* __restrict__ src, float* __restrict__ dst, int n,
                           const int* __restrict__ flag) {
  int i = blockIdx.x * 256 + threadIdx.x;
  if (i >= n) return;
  if (*flag) dst[i] = ((const float*)src)[i];
  else dst[i] = bfu(((const unsigned short*)src)[i]);
}

// Pack B[k][n] (K x NN) into MFMA 16x16x32 b-frag order from canonical f32.
__global__ void pack_b_kernel(const float* __restrict__ src, bf16* __restrict__ dst,
                              int K, int NN, int transpose) {
  int tid = blockIdx.x * 256 + threadIdx.x;
  if (tid >= K * NN) return;
  int NT = NN >> 4;
  int i = tid & 7;
  int lane = (tid >> 3) & 63;
  int rest = tid >> 9;
  int nt = rest % NT;
  int kt = rest / NT;
  int k = kt * 32 + ((lane >> 4) << 3) + i;
  int n = nt * 16 + (lane & 15);
  dst[tid] = __float2bfloat16(transpose ? src[n * K + k] : src[k * NN + n]);
}

// feat(bf16) = emb[text_idx], vectorized 8 elems/thread. grid*256 == N_NODES*16
__global__ void embed_v8_kernel(const int* __restrict__ idx, const void* __restrict__ emb_raw,
                                bf16* __restrict__ feat, const int* __restrict__ flag) {
  int tid = blockIdx.x * 256 + threadIdx.x;  // 800,000 exactly
  int n = tid >> 4, q = tid & 15;
  short8 o;
  if (*flag) {
    const float* e = (const float*)emb_raw + (size_t)idx[n] * 128 + q * 8;
    o = cvt8(e);
  } else {
    o = *(const short8*)((const unsigned short*)emb_raw + (size_t)idx[n] * 128 + q * 8);
  }
  *(short8*)(feat + (size_t)tid * 8) = o;
}

// counts via binary search on sorted gid (64 threads)
__global__ void count_bs_kernel(const int* __restrict__ gid, float* __restrict__ cnt) {
  int g = threadIdx.x;  // 0..63
  int lo = 0, hi = N_NODES;
  while (lo < hi) { int m = (lo + hi) >> 1; if (gid[m] < g) lo = m + 1; else hi = m; }
  int a0 = lo; hi = N_NODES;
  while (lo < hi) { int m = (lo + hi) >> 1; if (gid[m] < g + 1) lo = m + 1; else hi = m; }
  cnt[g] = (float)(lo - a0);
}

// sorted run-length segment sum: few atomics per block
__global__ void mean_sum_kernel(const bf16* __restrict__ feat, const int* __restrict__ gid,
                                float* __restrict__ gsum, int slot) {
  int n0 = blockIdx.x * 128;       // grid 391
  int h = threadIdx.x & 127;
  int r = threadIdx.x >> 7;        // 0..1
  float acc = 0.f; int curg = -1;
  for (int nn = r; nn < 128; nn += 2) {
    int node = n0 + nn;
    if (node >= N_NODES) break;
    int g = gid[node];
    if (g != curg) {
      if (curg >= 0) atomicAdd(&gsum[curg * 384 + slot * 128 + h], acc);
      curg = g; acc = 0.f;
    }
    acc += __bfloat162float(feat[(size_t)node * 128 + h]);
  }
  if (curg >= 0) atomicAdd(&gsum[curg * 384 + slot * 128 + h], acc);
}

// Wh3[e][n][128] = bf16( feat @ W_e + b_e ) for e=0..2, A-frags loaded once
__launch_bounds__(256)
__global__ void gemm_wh3_kernel(const bf16* __restrict__ A, const bf16* __restrict__ Bp,
                                const float* __restrict__ bias, bf16* __restrict__ C) {
  const int lane = threadIdx.x & 63;
  const int w = threadIdx.x >> 6;
  const int r0 = blockIdx.x * 64 + w * 16;
  int arow = r0 + (lane & 15);
  if (arow >= N_NODES) arow = N_NODES - 1;
  const int kb = (lane >> 4) << 3;
  short8 af[4];
#pragma unroll
  for (int kt = 0; kt < 4; ++kt)
    af[kt] = *(const short8*)(A + (size_t)arow * 128 + kt * 32 + kb);
  const int crow0 = r0 + ((lane >> 4) << 2);
  const int ccol = lane & 15;
  for (int e = 0; e < 3; ++e) {
    const bf16* Bpe = Bp + (size_t)e * 16384;
    const float* be = bias + e * 128;
    bf16* Ce = C + (size_t)e * N_NODES * 128;
#pragma unroll
    for (int nt = 0; nt < 8; ++nt) {
      f32x4 acc = {0.f, 0.f, 0.f, 0.f};
#pragma unroll
      for (int kt = 0; kt < 4; ++kt) {
        short8 bfr = *(const short8*)(Bpe + ((kt * 8 + nt) * 64 + lane) * 8);
        acc = __builtin_amdgcn_mfma_f32_16x16x32_bf16(af[kt], bfr, acc, 0, 0, 0);
      }
      float bv = be[nt * 16 + ccol];
#pragma unroll
      for (int rr = 0; rr < 4; ++rr) {
        int row = crow0 + rr;
        if (row < N_NODES) Ce[(size_t)row * 128 + nt * 16 + ccol] = __float2bfloat16(acc[rr] + bv);
      }
    }
  }
}

// single fused edge pass: a[dst] += Wh3[etype][src]
__global__ void edge_all_kernel(const int* __restrict__ src, const int* __restrict__ dst,
                                const int* __restrict__ et, const bf16* __restrict__ Wh3,
                                float* __restrict__ a) {
  int e = blockIdx.x * 4 + (threadIdx.x >> 6);
  int lane = threadIdx.x & 63;
  int s = src[e], d = dst[e], ty = et[e];
  unsigned u = *(const unsigned*)(Wh3 + ((size_t)ty * N_NODES + s) * 128 + lane * 2);
  atomicAdd(&a[(size_t)d * 128 + lane * 2],     bfu((unsigned short)(u & 0xffff)));
  atomicAdd(&a[(size_t)d * 128 + lane * 2 + 1], bfu((unsigned short)(u >> 16)));
}

// fallback pair (R9-passing path, used if ws is small)
__launch_bounds__(256)
__global__ void gemm_wh1_kernel(const bf16* __restrict__ A, const bf16* __restrict__ Bp,
                                const float* __restrict__ bias, bf16* __restrict__ C) {
  const int lane = threadIdx.x & 63;
  const int w = threadIdx.x >> 6;
  const int r0 = blockIdx.x * 64 + w * 16;
  int arow = r0 + (lane & 15);
  if (arow >= N_NODES) arow = N_NODES - 1;
  const int kb = (lane >> 4) << 3;
  short8 af[4];
#pragma unroll
  for (int kt = 0; kt < 4; ++kt)
    af[kt] = *(const short8*)(A + (size_t)arow * 128 + kt * 32 + kb);
  const int crow0 = r0 + ((lane >> 4) << 2);
  const int ccol = lane & 15;
#pragma unroll
  for (int nt = 0; nt < 8; ++nt) {
    f32x4 acc = {0.f, 0.f, 0.f, 0.f};
#pragma unroll
    for (int kt = 0; kt < 4; ++kt) {
      short8 bfr = *(const short8*)(Bp + ((kt * 8 + nt) * 64 + lane) * 8);
      acc = __builtin_amdgcn_mfma_f32_16x16x32_bf16(af[kt], bfr, acc, 0, 0, 0);
    }
    float bv = bias[nt * 16 + ccol];
#pragma unroll
    for (int rr = 0; rr < 4; ++rr) {
      int row = crow0 + rr;
      if (row < N_NODES) C[(size_t)row * 128 + nt * 16 + ccol] = __float2bfloat16(acc[rr] + bv);
    }
  }
}
__global__ void edge_kernel(const int* __restrict__ src, const int* __restrict__ dst,
                            const int* __restrict__ et, const bf16* __restrict__ Wh,
                            float* __restrict__ a, int pass) {
  int e = blockIdx.x * 4 + (threadIdx.x >> 6);
  if (et[e] != pass) return;
  int lane = threadIdx.x & 63;
  int s = src[e], d = dst[e];
  unsigned u = *(const unsigned*)(Wh + (size_t)s * 128 + lane * 2);
  atomicAdd(&a[(size_t)d * 128 + lane * 2],     bfu((unsigned short)(u & 0xffff)));
  atomicAdd(&a[(size_t)d * 128 + lane * 2 + 1], bfu((unsigned short)(u >> 16)));
}

// Fused: gi = a@Wih^T+bih, gh = feat@Whh^T+bhh, GRU gate, feat(bf16) update in place.
__launch_bounds__(256)
__global__ void gru_kernel(const float* __restrict__ a, bf16* __restrict__ feat,
                           const bf16* __restrict__ Bih, const bf16* __restrict__ Bhh,
                           const float* __restrict__ bih, const float* __restrict__ bhh) {
  const int lane = threadIdx.x & 63;
  const int w = threadIdx.x >> 6;
  const int r0 = blockIdx.x * 64 + w * 16;
  int arow = r0 + (lane & 15);
  if (arow >= N_NODES) arow = N_NODES - 1;
  const int kb = (lane >> 4) << 3;
  short8 fa[4], fh[4];
#pragma unroll
  for (int kt = 0; kt < 4; ++kt) {
    fa[kt] = cvt8(a + (size_t)arow * 128 + kt * 32 + kb);
    fh[kt] = *(const short8*)(feat + (size_t)arow * 128 + kt * 32 + kb);
  }
  const int crow0 = r0 + ((lane >> 4) << 2);
  const int ccol = lane & 15;
  f32x4 rg[8], zg[8];
#pragma unroll
  for (int g = 0; g < 3; ++g) {
#pragma unroll
    for (int nt = 0; nt < 8; ++nt) {
      const int ntg = g * 8 + nt;
      f32x4 gi = {0.f, 0.f, 0.f, 0.f}, gh = {0.f, 0.f, 0.f, 0.f};
#pragma unroll
      for (int kt = 0; kt < 4; ++kt) {
        short8 bi = *(const short8*)(Bih + ((size_t)(kt * 24 + ntg) * 64 + lane) * 8);
        short8 bh = *(const short8*)(Bhh + ((size_t)(kt * 24 + ntg) * 64 + lane) * 8);
        gi = __builtin_amdgcn_mfma_f32_16x16x32_bf16(fa[kt], bi, gi, 0, 0, 0);
        gh = __builtin_amdgcn_mfma_f32_16x16x32_bf16(fh[kt], bh, gh, 0, 0, 0);
      }
      float bvi = bih[ntg * 16 + ccol];
      float bvh = bhh[ntg * 16 + ccol];
      if (g == 0) {
#pragma unroll
        for (int rr = 0; rr < 4; ++rr)
          rg[nt][rr] = 1.f / (1.f + __expf(-(gi[rr] + bvi + gh[rr] + bvh)));
      } else if (g == 1) {
#pragma unroll
        for (int rr = 0; rr < 4; ++rr)
          zg[nt][rr] = 1.f / (1.f + __expf(-(gi[rr] + bvi + gh[rr] + bvh)));
      } else {
#pragma unroll
        for (int rr = 0; rr < 4; ++rr) {
          int row = crow0 + rr;
          if (row < N_NODES) {
            int col = nt * 16 + ccol;
            float hn = gh[rr] + bvh;
            float nc = tanhf(gi[rr] + bvi + rg[nt][rr] * hn);
            float hv = __bfloat162float(feat[(size_t)row * 128 + col]);
            float z = zg[nt][rr];
            feat[(size_t)row * 128 + col] = __float2bfloat16((1.f - z) * nc + z * hv);
          }
        }
      }
    }
  }
}

// OUTPUT IS FLOAT32 (reference returns jax f32 arrays).
__global__ void final_kernel(const float* __restrict__ gsum, const float* __restrict__ cnt,
                             const float* __restrict__ W1, const float* __restrict__ b1,
                             const float* __restrict__ W2, const float* __restrict__ b2,
                             float* __restrict__ out) {
  __shared__ float ga[384];
  __shared__ float red[2];
  int g = blockIdx.x, t = threadIdx.x;
  float c = fmaxf(cnt[g], 1.f);
  for (int k = t; k < 384; k += 128) {
    float m = gsum[g * 384 + k] / c;
    ga[k] = m;
    out[64 + g * 384 + k] = m;
  }
  __syncthreads();
  float acc = b1[t];
  for (int k = 0; k < 384; ++k) acc += ga[k] * W1[k * 128 + t];
  float x = fmaxf(acc, 0.f);
  float pv = x * W2[t];
#pragma unroll
  for (int off = 32; off > 0; off >>= 1) pv += __shfl_down(pv, off);
  if ((t & 63) == 0) red[t >> 6] = pv;
  __syncthreads();
  if (t == 0) out[g] = red[0] + red[1] + b2[0];
}

extern "C" void kernel_launch(void* const* d_in, const int* in_sizes, int n_in,
                              void* d_out, int out_size, void* d_ws, size_t ws_size,
                              hipStream_t stream) {
  const int* text_idx = (const int*)d_in[0];
  const int* srcp     = (const int*)d_in[1];
  const int* dstp     = (const int*)d_in[2];
  const int* etype    = (const int*)d_in[3];
  const int* gid      = (const int*)d_in[4];
  float* out = (float*)d_out;
  float* ws = (float*)d_ws;

  const bool big = ws_size >= (size_t)82000000;

  bf16*  feat = (bf16*)ws;                 // 6.4M bf16
  float* a    = ws + 3200000;              // 6.4M f32
  bf16*  Wh   = (bf16*)(ws + 9600000);     // big: [3][N][128] (19.2M bf16); small: [N][128]
  bf16*  packWe;
  float* canon;
  float* gsum;
  if (big) {
    packWe = (bf16*)(ws + 19200000);
    canon  = ws + 19347456;
    gsum   = ws + 19694096;
  } else {
    packWe = (bf16*)(ws + 12800000);
    canon  = ws + 12947456;
    gsum   = ws + 13294096;
  }
  bf16* packWih = packWe + 98304;
  bf16* packWhh = packWih + 98304;
  float* cWl  = canon;
  float* cWih = canon + 98304;
  float* cWhh = canon + 196608;
  float* cbl  = canon + 294912;
  float* cbih = canon + 295680;
  float* cbhh = canon + 296448;
  float* cW1  = canon + 297216;
  float* cb1  = canon + 346368;
  float* cW2  = canon + 346496;
  float* cb2  = canon + 346624;
  float* cnt  = gsum + 24576;
  int*   fflag = (int*)(cnt + 64);

  detect_f_kernel<<<1, 64, 0, stream>>>((const unsigned short*)d_in[5], fflag);

  cvt_kernel<<<384, 256, 0, stream>>>(d_in[6],  cWl,  98304, fflag);
  cvt_kernel<<<3,   256, 0, stream>>>(d_in[7],  cbl,  768,   fflag);
  cvt_kernel<<<384, 256, 0, stream>>>(d_in[8],  cWih, 98304, fflag);
  cvt_kernel<<<384, 256, 0, stream>>>(d_in[9],  cWhh, 98304, fflag);
  cvt_kernel<<<3,   256, 0, stream>>>(d_in[10], cbih, 768,   fflag);
  cvt_kernel<<<3,   256, 0, stream>>>(d_in[11], cbhh, 768,   fflag);
  cvt_kernel<<<192, 256, 0, stream>>>(d_in[12], cW1,  49152, fflag);
  cvt_kernel<<<1,   256, 0, stream>>>(d_in[13], cb1,  128,   fflag);
  cvt_kernel<<<1,   256, 0, stream>>>(d_in[14], cW2,  128,   fflag);
  cvt_kernel<<<1,   256, 0, stream>>>(d_in[15], cb2,  1,     fflag);

  hipMemsetAsync(gsum, 0, 24576 * sizeof(float), stream);

  for (int m = 0; m < 6; ++m)
    pack_b_kernel<<<64, 256, 0, stream>>>(cWl + m * 16384, packWe + m * 16384, 128, 128, 0);
  for (int l = 0; l < 2; ++l) {
    pack_b_kernel<<<192, 256, 0, stream>>>(cWih + l * 49152, packWih + l * 49152, 128, 384, 1);
    pack_b_kernel<<<192, 256, 0, stream>>>(cWhh + l * 49152, packWhh + l * 49152, 128, 384, 1);
  }

  embed_v8_kernel<<<3125, 256, 0, stream>>>(text_idx, d_in[5], feat, fflag);
  count_bs_kernel<<<1, 64, 0, stream>>>(gid, cnt);
  mean_sum_kernel<<<391, 256, 0, stream>>>(feat, gid, gsum, 0);

  for (int l = 0; l < 2; ++l) {
    for (int s = 0; s < 2; ++s) {
      hipMemsetAsync(a, 0, 6400000 * sizeof(float), stream);
      if (big) {
        gemm_wh3_kernel<<<782, 256, 0, stream>>>(feat, packWe + l * 3 * 16384,
                                                 cbl + l * 384, Wh);
        edge_all_kernel<<<150000, 256, 0, stream>>>(srcp, dstp, etype, Wh, a);
      } else {
        for (int t = 0; t < 3; ++t) {
          gemm_wh1_kernel<<<782, 256, 0, stream>>>(feat, packWe + (l * 3 + t) * 16384,
                                                   cbl + l * 384 + t * 128, Wh);
          edge_kernel<<<150000, 256, 0, stream>>>(srcp, dstp, etype, Wh, a, t);
        }
      }
      gru_kernel<<<782, 256, 0, stream>>>(a, feat, packWih + l * 49152, packWhh + l * 49152,
                                          cbih + l * 384, cbhh + l * 384);
    }
    mean_sum_kernel<<<391, 256, 0, stream>>>(feat, gid, gsum, l + 1);
  }

  final_kernel<<<64, 128, 0, stream>>>(gsum, cnt, cW1, cb1, cW2, cb2, out);
}

// Round 11
// 1056.207 us; speedup vs baseline: 2.9690x; 2.4824x over previous
//
#include <hip/hip_runtime.h>
#include <hip/hip_bf16.h>

#define N_NODES 50000
#define N_EDGES 600000
#define N_GRAPHS 64
#define CHUNK 196  // 256*196 >= 50000

typedef __hip_bfloat16 bf16;
typedef __attribute__((ext_vector_type(8))) short short8;
typedef __attribute__((ext_vector_type(4))) float f32x4;

static __device__ inline short bfbits(float x) {
  union { bf16 h; short s; } u;
  u.h = __float2bfloat16(x);
  return u.s;
}
static __device__ inline float bfu(unsigned short s) {
  union { float f; unsigned u; } x; x.u = ((unsigned)s) << 16; return x.f;
}
static __device__ inline short8 cvt8(const float* p) {
  f32x4 v0 = *(const f32x4*)p, v1 = *(const f32x4*)(p + 4);
  short8 r;
  r[0] = bfbits(v0[0]); r[1] = bfbits(v0[1]); r[2] = bfbits(v0[2]); r[3] = bfbits(v0[3]);
  r[4] = bfbits(v1[0]); r[5] = bfbits(v1[1]); r[6] = bfbits(v1[2]); r[7] = bfbits(v1[3]);
  return r;
}

// float dtype detection: bf16 (flag=0) or float32 (flag=1)?  (R5 verified: f32)
__global__ void detect_f_kernel(const unsigned short* __restrict__ raw, int* __restrict__ flag) {
  int t = threadIdx.x;  // 64
  int wild = 0;
  for (int i = 0; i < 4; ++i) {
    unsigned short u = raw[t * 4 + i];
    int e = (u >> 7) & 0xFF;
    if (u != 0 && (e < 96 || e > 159)) wild++;
  }
#pragma unroll
  for (int off = 32; off > 0; off >>= 1) wild += __shfl_down(wild, off);
  if (t == 0) *flag = (wild >= 32) ? 1 : 0;
}

__global__ void cvt_kernel(const void* __restrict__ src, float* __restrict__ dst, int n,
                           const int* __restrict__ flag) {
  int i = blockIdx.x * 256 + threadIdx.x;
  if (i >= n) return;
  if (*flag) dst[i] = ((const float*)src)[i];
  else dst[i] = bfu(((const unsigned short*)src)[i]);
}

__global__ void pack_b_kernel(const float* __restrict__ src, bf16* __restrict__ dst,
                              int K, int NN, int transpose) {
  int tid = blockIdx.x * 256 + threadIdx.x;
  if (tid >= K * NN) return;
  int NT = NN >> 4;
  int i = tid & 7;
  int lane = (tid >> 3) & 63;
  int rest = tid >> 9;
  int nt = rest % NT;
  int kt = rest / NT;
  int k = kt * 32 + ((lane >> 4) << 3) + i;
  int n = nt * 16 + (lane & 15);
  dst[tid] = __float2bfloat16(transpose ? src[n * K + k] : src[k * NN + n]);
}

__global__ void embed_v8_kernel(const int* __restrict__ idx, const void* __restrict__ emb_raw,
                                bf16* __restrict__ feat, const int* __restrict__ flag) {
  int tid = blockIdx.x * 256 + threadIdx.x;  // 800,000 exactly
  int n = tid >> 4, q = tid & 15;
  short8 o;
  if (*flag) {
    o = cvt8((const float*)emb_raw + (size_t)idx[n] * 128 + q * 8);
  } else {
    o = *(const short8*)((const unsigned short*)emb_raw + (size_t)idx[n] * 128 + q * 8);
  }
  *(short8*)(feat + (size_t)tid * 8) = o;
}

__global__ void count_bs_kernel(const int* __restrict__ gid, float* __restrict__ cnt) {
  int g = threadIdx.x;  // 0..63
  int lo = 0, hi = N_NODES;
  while (lo < hi) { int m = (lo + hi) >> 1; if (gid[m] < g) lo = m + 1; else hi = m; }
  int a0 = lo; hi = N_NODES;
  while (lo < hi) { int m = (lo + hi) >> 1; if (gid[m] < g + 1) lo = m + 1; else hi = m; }
  cnt[g] = (float)(lo - a0);
}

__global__ void mean_sum_kernel(const bf16* __restrict__ feat, const int* __restrict__ gid,
                                float* __restrict__ gsum, int slot) {
  int n0 = blockIdx.x * 128;       // grid 391
  int h = threadIdx.x & 127;
  int r = threadIdx.x >> 7;
  float acc = 0.f; int curg = -1;
  for (int nn = r; nn < 128; nn += 2) {
    int node = n0 + nn;
    if (node >= N_NODES) break;
    int g = gid[node];
    if (g != curg) {
      if (curg >= 0) atomicAdd(&gsum[curg * 384 + slot * 128 + h], acc);
      curg = g; acc = 0.f;
    }
    acc += __bfloat162float(feat[(size_t)node * 128 + h]);
  }
  if (curg >= 0) atomicAdd(&gsum[curg * 384 + slot * 128 + h], acc);
}

// ---------- CSR build (once per launch; graph static across steps) ----------
__global__ void hist_kernel(const int* __restrict__ dst, int* __restrict__ deg) {
  int e = blockIdx.x * 256 + threadIdx.x;
  if (e < N_EDGES) atomicAdd(&deg[dst[e]], 1);
}
__global__ void scan_chunks_kernel(const int* __restrict__ deg, int* __restrict__ csums) {
  int t = threadIdx.x;  // 256
  int beg = t * CHUNK, end = min(beg + CHUNK, N_NODES);
  int s = 0;
  for (int i = beg; i < end; ++i) s += deg[i];
  csums[t] = s;
}
__global__ void scan_write_kernel(const int* __restrict__ deg, const int* __restrict__ csums,
                                  int* __restrict__ off, int* __restrict__ cur) {
  int t = threadIdx.x;  // 256
  int base = 0;
  for (int j = 0; j < t; ++j) base += csums[j];
  int beg = t * CHUNK, end = min(beg + CHUNK, N_NODES);
  for (int i = beg; i < end; ++i) { off[i] = base; cur[i] = base; base += deg[i]; }
  if (t == 255) off[N_NODES] = base;  // == N_EDGES
}
__global__ void scatter_kernel(const int* __restrict__ src, const int* __restrict__ dst,
                               const int* __restrict__ et, int* __restrict__ cur,
                               int* __restrict__ val) {
  int e = blockIdx.x * 256 + threadIdx.x;
  if (e >= N_EDGES) return;
  int pos = atomicAdd(&cur[dst[e]], 1);
  val[pos] = src[e] | (et[e] << 16);   // src < 2^16, et < 4
}

// Wh3[e][n][128] = bf16( feat @ W_e + b_e ) for e=0..2, A-frags loaded once
__launch_bounds__(256)
__global__ void gemm_wh3_kernel(const bf16* __restrict__ A, const bf16* __restrict__ Bp,
                                const float* __restrict__ bias, bf16* __restrict__ C) {
  const int lane = threadIdx.x & 63;
  const int w = threadIdx.x >> 6;
  const int r0 = blockIdx.x * 64 + w * 16;
  int arow = r0 + (lane & 15);
  if (arow >= N_NODES) arow = N_NODES - 1;
  const int kb = (lane >> 4) << 3;
  short8 af[4];
#pragma unroll
  for (int kt = 0; kt < 4; ++kt)
    af[kt] = *(const short8*)(A + (size_t)arow * 128 + kt * 32 + kb);
  const int crow0 = r0 + ((lane >> 4) << 2);
  const int ccol = lane & 15;
  for (int e = 0; e < 3; ++e) {
    const bf16* Bpe = Bp + (size_t)e * 16384;
    const float* be = bias + e * 128;
    bf16* Ce = C + (size_t)e * N_NODES * 128;
#pragma unroll
    for (int nt = 0; nt < 8; ++nt) {
      f32x4 acc = {0.f, 0.f, 0.f, 0.f};
#pragma unroll
      for (int kt = 0; kt < 4; ++kt) {
        short8 bfr = *(const short8*)(Bpe + ((kt * 8 + nt) * 64 + lane) * 8);
        acc = __builtin_amdgcn_mfma_f32_16x16x32_bf16(af[kt], bfr, acc, 0, 0, 0);
      }
      float bv = be[nt * 16 + ccol];
#pragma unroll
      for (int rr = 0; rr < 4; ++rr) {
        int row = crow0 + rr;
        if (row < N_NODES) Ce[(size_t)row * 128 + nt * 16 + ccol] = __float2bfloat16(acc[rr] + bv);
      }
    }
  }
}

// one wave per dst: a[d] = sum of Wh3[ty][s] over in-edges (register accum, no atomics)
__launch_bounds__(256)
__global__ void edge_gather_kernel(const int* __restrict__ off, const int* __restrict__ val,
                                   const bf16* __restrict__ Wh3, bf16* __restrict__ a) {
  int d = blockIdx.x * 4 + (threadIdx.x >> 6);
  if (d >= N_NODES) return;
  int lane = threadIdx.x & 63;
  int e1 = off[d + 1];
  float a0 = 0.f, a1 = 0.f;
  for (int e = off[d]; e < e1; ++e) {
    int v = val[e];
    int s = v & 0xFFFF, ty = v >> 16;
    unsigned u = *(const unsigned*)(Wh3 + ((size_t)ty * N_NODES + s) * 128 + lane * 2);
    a0 += bfu((unsigned short)(u & 0xffff));
    a1 += bfu((unsigned short)(u >> 16));
  }
  unsigned o = ((unsigned)(unsigned short)bfbits(a1) << 16) | (unsigned short)bfbits(a0);
  *(unsigned*)(a + (size_t)d * 128 + lane * 2) = o;
}

// ---------- fallback small-ws path (R10-proven) ----------
__launch_bounds__(256)
__global__ void gemm_wh1_kernel(const bf16* __restrict__ A, const bf16* __restrict__ Bp,
                                const float* __restrict__ bias, bf16* __restrict__ C) {
  const int lane = threadIdx.x & 63;
  const int w = threadIdx.x >> 6;
  const int r0 = blockIdx.x * 64 + w * 16;
  int arow = r0 + (lane & 15);
  if (arow >= N_NODES) arow = N_NODES - 1;
  const int kb = (lane >> 4) << 3;
  short8 af[4];
#pragma unroll
  for (int kt = 0; kt < 4; ++kt)
    af[kt] = *(const short8*)(A + (size_t)arow * 128 + kt * 32 + kb);
  const int crow0 = r0 + ((lane >> 4) << 2);
  const int ccol = lane & 15;
#pragma unroll
  for (int nt = 0; nt < 8; ++nt) {
    f32x4 acc = {0.f, 0.f, 0.f, 0.f};
#pragma unroll
    for (int kt = 0; kt < 4; ++kt) {
      short8 bfr = *(const short8*)(Bp + ((kt * 8 + nt) * 64 + lane) * 8);
      acc = __builtin_amdgcn_mfma_f32_16x16x32_bf16(af[kt], bfr, acc, 0, 0, 0);
    }
    float bv = bias[nt * 16 + ccol];
#pragma unroll
    for (int rr = 0; rr < 4; ++rr) {
      int row = crow0 + rr;
      if (row < N_NODES) C[(size_t)row * 128 + nt * 16 + ccol] = __float2bfloat16(acc[rr] + bv);
    }
  }
}
__global__ void edge_kernel(const int* __restrict__ src, const int* __restrict__ dst,
                            const int* __restrict__ et, const bf16* __restrict__ Wh,
                            float* __restrict__ a, int pass) {
  int e = blockIdx.x * 4 + (threadIdx.x >> 6);
  if (et[e] != pass) return;
  int lane = threadIdx.x & 63;
  int s = src[e], d = dst[e];
  unsigned u = *(const unsigned*)(Wh + (size_t)s * 128 + lane * 2);
  atomicAdd(&a[(size_t)d * 128 + lane * 2],     bfu((unsigned short)(u & 0xffff)));
  atomicAdd(&a[(size_t)d * 128 + lane * 2 + 1], bfu((unsigned short)(u >> 16)));
}
__global__ void cvt_a_kernel(const float* __restrict__ af, bf16* __restrict__ ab) {
  int i = blockIdx.x * 256 + threadIdx.x;  // 6.4M
  ab[i] = __float2bfloat16(af[i]);
}
// ----------------------------------------------------------

// Fused GRU: gi = a@Wih^T+bih, gh = feat@Whh^T+bhh, gate, feat(bf16) in-place. a is bf16.
__launch_bounds__(256)
__global__ void gru_kernel(const bf16* __restrict__ a, bf16* __restrict__ feat,
                           const bf16* __restrict__ Bih, const bf16* __restrict__ Bhh,
                           const float* __restrict__ bih, const float* __restrict__ bhh) {
  const int lane = threadIdx.x & 63;
  const int w = threadIdx.x >> 6;
  const int r0 = blockIdx.x * 64 + w * 16;
  int arow = r0 + (lane & 15);
  if (arow >= N_NODES) arow = N_NODES - 1;
  const int kb = (lane >> 4) << 3;
  short8 fa[4], fh[4];
#pragma unroll
  for (int kt = 0; kt < 4; ++kt) {
    fa[kt] = *(const short8*)(a + (size_t)arow * 128 + kt * 32 + kb);
    fh[kt] = *(const short8*)(feat + (size_t)arow * 128 + kt * 32 + kb);
  }
  const int crow0 = r0 + ((lane >> 4) << 2);
  const int ccol = lane & 15;
  f32x4 rg[8], zg[8];
#pragma unroll
  for (int g = 0; g < 3; ++g) {
#pragma unroll
    for (int nt = 0; nt < 8; ++nt) {
      const int ntg = g * 8 + nt;
      f32x4 gi = {0.f, 0.f, 0.f, 0.f}, gh = {0.f, 0.f, 0.f, 0.f};
#pragma unroll
      for (int kt = 0; kt < 4; ++kt) {
        short8 bi = *(const short8*)(Bih + ((size_t)(kt * 24 + ntg) * 64 + lane) * 8);
        short8 bh = *(const short8*)(Bhh + ((size_t)(kt * 24 + ntg) * 64 + lane) * 8);
        gi = __builtin_amdgcn_mfma_f32_16x16x32_bf16(fa[kt], bi, gi, 0, 0, 0);
        gh = __builtin_amdgcn_mfma_f32_16x16x32_bf16(fh[kt], bh, gh, 0, 0, 0);
      }
      float bvi = bih[ntg * 16 + ccol];
      float bvh = bhh[ntg * 16 + ccol];
      if (g == 0) {
#pragma unroll
        for (int rr = 0; rr < 4; ++rr)
          rg[nt][rr] = 1.f / (1.f + __expf(-(gi[rr] + bvi + gh[rr] + bvh)));
      } else if (g == 1) {
#pragma unroll
        for (int rr = 0; rr < 4; ++rr)
          zg[nt][rr] = 1.f / (1.f + __expf(-(gi[rr] + bvi + gh[rr] + bvh)));
      } else {
#pragma unroll
        for (int rr = 0; rr < 4; ++rr) {
          int row = crow0 + rr;
          if (row < N_NODES) {
            int col = nt * 16 + ccol;
            float hn = gh[rr] + bvh;
            float nc = tanhf(gi[rr] + bvi + rg[nt][rr] * hn);
            float hv = __bfloat162float(feat[(size_t)row * 128 + col]);
            float z = zg[nt][rr];
            feat[(size_t)row * 128 + col] = __float2bfloat16((1.f - z) * nc + z * hv);
          }
        }
      }
    }
  }
}

// OUTPUT IS FLOAT32 (reference returns jax f32 arrays).
__global__ void final_kernel(const float* __restrict__ gsum, const float* __restrict__ cnt,
                             const float* __restrict__ W1, const float* __restrict__ b1,
                             const float* __restrict__ W2, const float* __restrict__ b2,
                             float* __restrict__ out) {
  __shared__ float ga[384];
  __shared__ float red[2];
  int g = blockIdx.x, t = threadIdx.x;
  float c = fmaxf(cnt[g], 1.f);
  for (int k = t; k < 384; k += 128) {
    float m = gsum[g * 384 + k] / c;
    ga[k] = m;
    out[64 + g * 384 + k] = m;
  }
  __syncthreads();
  float acc = b1[t];
  for (int k = 0; k < 384; ++k) acc += ga[k] * W1[k * 128 + t];
  float x = fmaxf(acc, 0.f);
  float pv = x * W2[t];
#pragma unroll
  for (int off = 32; off > 0; off >>= 1) pv += __shfl_down(pv, off);
  if ((t & 63) == 0) red[t >> 6] = pv;
  __syncthreads();
  if (t == 0) out[g] = red[0] + red[1] + b2[0];
}

extern "C" void kernel_launch(void* const* d_in, const int* in_sizes, int n_in,
                              void* d_out, int out_size, void* d_ws, size_t ws_size,
                              hipStream_t stream) {
  const int* text_idx = (const int*)d_in[0];
  const int* srcp     = (const int*)d_in[1];
  const int* dstp     = (const int*)d_in[2];
  const int* etype    = (const int*)d_in[3];
  const int* gid      = (const int*)d_in[4];
  float* out = (float*)d_out;
  float* ws = (float*)d_ws;

  const bool big = ws_size >= (size_t)82000000;  // big path confirmed running in R10

  bf16 *feat, *abf, *Wh, *packWe;
  float *af32 = nullptr, *canon, *gsum;
  int *csr_off = nullptr, *csr_cur = nullptr, *csr_deg = nullptr, *csr_val = nullptr,
      *csr_csums = nullptr;
  if (big) {
    feat   = (bf16*)ws;                      // [0, 3.2M) fl
    abf    = (bf16*)(ws + 3200000);          // [3.2M, 6.4M) fl
    Wh     = (bf16*)(ws + 6400000);          // [6.4M, 16.0M) fl  ([3][N][128] bf16)
    packWe = (bf16*)(ws + 16000000);
    canon  = ws + 16147456;
    gsum   = ws + 16494096;
    csr_off   = (int*)(ws + 16518744);       // 50001
    csr_cur   = csr_off + 50001;             // 50001
    csr_deg   = csr_cur + 50001;             // 50000
    csr_val   = csr_deg + 50000;             // 600000
    csr_csums = csr_val + 600000;            // 256   (end ~16.72M fl = 66.9MB)
  } else {
    feat   = (bf16*)ws;
    af32   = ws + 3200000;                   // f32 [N][128]
    Wh     = (bf16*)(ws + 9600000);          // [N][128] bf16; reused as abf after cvt
    packWe = (bf16*)(ws + 12800000);
    canon  = ws + 12947456;
    gsum   = ws + 13294096;
    abf    = Wh;
  }
  bf16* packWih = packWe + 98304;
  bf16* packWhh = packWih + 98304;
  float* cWl  = canon;
  float* cWih = canon + 98304;
  float* cWhh = canon + 196608;
  float* cbl  = canon + 294912;
  float* cbih = canon + 295680;
  float* cbhh = canon + 296448;
  float* cW1  = canon + 297216;
  float* cb1  = canon + 346368;
  float* cW2  = canon + 346496;
  float* cb2  = canon + 346624;
  float* cnt  = gsum + 24576;
  int*   fflag = (int*)(cnt + 64);

  detect_f_kernel<<<1, 64, 0, stream>>>((const unsigned short*)d_in[5], fflag);

  cvt_kernel<<<384, 256, 0, stream>>>(d_in[6],  cWl,  98304, fflag);
  cvt_kernel<<<3,   256, 0, stream>>>(d_in[7],  cbl,  768,   fflag);
  cvt_kernel<<<384, 256, 0, stream>>>(d_in[8],  cWih, 98304, fflag);
  cvt_kernel<<<384, 256, 0, stream>>>(d_in[9],  cWhh, 98304, fflag);
  cvt_kernel<<<3,   256, 0, stream>>>(d_in[10], cbih, 768,   fflag);
  cvt_kernel<<<3,   256, 0, stream>>>(d_in[11], cbhh, 768,   fflag);
  cvt_kernel<<<192, 256, 0, stream>>>(d_in[12], cW1,  49152, fflag);
  cvt_kernel<<<1,   256, 0, stream>>>(d_in[13], cb1,  128,   fflag);
  cvt_kernel<<<1,   256, 0, stream>>>(d_in[14], cW2,  128,   fflag);
  cvt_kernel<<<1,   256, 0, stream>>>(d_in[15], cb2,  1,     fflag);

  hipMemsetAsync(gsum, 0, 24576 * sizeof(float), stream);

  for (int m = 0; m < 6; ++m)
    pack_b_kernel<<<64, 256, 0, stream>>>(cWl + m * 16384, packWe + m * 16384, 128, 128, 0);
  for (int l = 0; l < 2; ++l) {
    pack_b_kernel<<<192, 256, 0, stream>>>(cWih + l * 49152, packWih + l * 49152, 128, 384, 1);
    pack_b_kernel<<<192, 256, 0, stream>>>(cWhh + l * 49152, packWhh + l * 49152, 128, 384, 1);
  }

  if (big) {  // build CSR once (graph static across all 4 steps)
    hipMemsetAsync(csr_deg, 0, 50000 * sizeof(int), stream);
    hist_kernel<<<2344, 256, 0, stream>>>(dstp, csr_deg);
    scan_chunks_kernel<<<1, 256, 0, stream>>>(csr_deg, csr_csums);
    scan_write_kernel<<<1, 256, 0, stream>>>(csr_deg, csr_csums, csr_off, csr_cur);
    scatter_kernel<<<2344, 256, 0, stream>>>(srcp, dstp, etype, csr_cur, csr_val);
  }

  embed_v8_kernel<<<3125, 256, 0, stream>>>(text_idx, d_in[5], feat, fflag);
  count_bs_kernel<<<1, 64, 0, stream>>>(gid, cnt);
  mean_sum_kernel<<<391, 256, 0, stream>>>(feat, gid, gsum, 0);

  for (int l = 0; l < 2; ++l) {
    for (int s = 0; s < 2; ++s) {
      if (big) {
        gemm_wh3_kernel<<<782, 256, 0, stream>>>(feat, packWe + l * 3 * 16384,
                                                 cbl + l * 384, Wh);
        edge_gather_kernel<<<12500, 256, 0, stream>>>(csr_off, csr_val, Wh, abf);
      } else {
        hipMemsetAsync(af32, 0, 6400000 * sizeof(float), stream);
        for (int t = 0; t < 3; ++t) {
          gemm_wh1_kernel<<<782, 256, 0, stream>>>(feat, packWe + (l * 3 + t) * 16384,
                                                   cbl + l * 384 + t * 128, Wh);
          edge_kernel<<<150000, 256, 0, stream>>>(srcp, dstp, etype, Wh, af32, t);
        }
        cvt_a_kernel<<<25000, 256, 0, stream>>>(af32, abf);
      }
      gru_kernel<<<782, 256, 0, stream>>>(abf, feat, packWih + l * 49152, packWhh + l * 49152,
                                          cbih + l * 384, cbhh + l * 384);
    }
    mean_sum_kernel<<<391, 256, 0, stream>>>(feat, gid, gsum, l + 1);
  }

  final_kernel<<<64, 128, 0, stream>>>(gsum, cnt, cW1, cb1, cW2, cb2, out);
}

// Round 12
// 915.253 us; speedup vs baseline: 3.4262x; 1.1540x over previous
//
#include <hip/hip_runtime.h>
#include <hip/hip_bf16.h>

#define N_NODES 50000
#define N_EDGES 600000
#define N_GRAPHS 64
#define CHUNK 196  // 256*196 >= 50000

typedef __hip_bfloat16 bf16;
typedef __attribute__((ext_vector_type(8))) short short8;
typedef __attribute__((ext_vector_type(4))) float f32x4;

static __device__ inline short bfbits(float x) {
  union { bf16 h; short s; } u;
  u.h = __float2bfloat16(x);
  return u.s;
}
static __device__ inline float bfu(unsigned short s) {
  union { float f; unsigned u; } x; x.u = ((unsigned)s) << 16; return x.f;
}
static __device__ inline short8 cvt8(const float* p) {
  f32x4 v0 = *(const f32x4*)p, v1 = *(const f32x4*)(p + 4);
  short8 r;
  r[0] = bfbits(v0[0]); r[1] = bfbits(v0[1]); r[2] = bfbits(v0[2]); r[3] = bfbits(v0[3]);
  r[4] = bfbits(v1[0]); r[5] = bfbits(v1[1]); r[6] = bfbits(v1[2]); r[7] = bfbits(v1[3]);
  return r;
}

// float dtype detection: bf16 (flag=0) or float32 (flag=1)?  (R5 verified: f32)
__global__ void detect_f_kernel(const unsigned short* __restrict__ raw, int* __restrict__ flag) {
  int t = threadIdx.x;  // 64
  int wild = 0;
  for (int i = 0; i < 4; ++i) {
    unsigned short u = raw[t * 4 + i];
    int e = (u >> 7) & 0xFF;
    if (u != 0 && (e < 96 || e > 159)) wild++;
  }
#pragma unroll
  for (int off = 32; off > 0; off >>= 1) wild += __shfl_down(wild, off);
  if (t == 0) *flag = (wild >= 32) ? 1 : 0;
}

// all 10 small float params -> canon, one launch
struct CvtArgs { const void* p[10]; };
__global__ void cvt_all_kernel(CvtArgs args, float* __restrict__ canon,
                               const int* __restrict__ flag) {
  int i = blockIdx.x * 256 + threadIdx.x;
  if (i >= 346625) return;
  const int offs[11] = {0, 98304, 196608, 294912, 295680, 296448,
                        297216, 346368, 346496, 346624, 346625};
  int seg = 0;
#pragma unroll
  for (int k = 1; k < 10; ++k) if (i >= offs[k]) seg = k;
  int j = i - offs[seg];
  const void* s = args.p[seg];
  canon[i] = (*flag) ? ((const float*)s)[j] : bfu(((const unsigned short*)s)[j]);
}

// all weight packs in one launch (294,912 elements)
__global__ void pack_all_kernel(const float* __restrict__ cWl, const float* __restrict__ cWih,
                                const float* __restrict__ cWhh, bf16* __restrict__ packWe,
                                bf16* __restrict__ packWih, bf16* __restrict__ packWhh) {
  int tid = blockIdx.x * 256 + threadIdx.x;
  if (tid >= 294912) return;
  const float* src; bf16* dst; int NN, transpose, within;
  if (tid < 98304) {
    int m = tid >> 14; within = tid & 16383;
    src = cWl + m * 16384; dst = packWe + m * 16384; NN = 128; transpose = 0;
  } else if (tid < 196608) {
    int t2 = tid - 98304; int l = t2 / 49152; within = t2 % 49152;
    src = cWih + l * 49152; dst = packWih + l * 49152; NN = 384; transpose = 1;
  } else {
    int t2 = tid - 196608; int l = t2 / 49152; within = t2 % 49152;
    src = cWhh + l * 49152; dst = packWhh + l * 49152; NN = 384; transpose = 1;
  }
  int NT = NN >> 4;
  int i = within & 7;
  int lane = (within >> 3) & 63;
  int rest = within >> 9;
  int nt = rest % NT, kt = rest / NT;
  int k = kt * 32 + ((lane >> 4) << 3) + i;
  int n = nt * 16 + (lane & 15);
  dst[within] = __float2bfloat16(transpose ? src[n * 128 + k] : src[k * NN + n]);
}

__global__ void embed_v8_kernel(const int* __restrict__ idx, const void* __restrict__ emb_raw,
                                bf16* __restrict__ feat, const int* __restrict__ flag) {
  int tid = blockIdx.x * 256 + threadIdx.x;  // 800,000 exactly
  int n = tid >> 4, q = tid & 15;
  short8 o;
  if (*flag) {
    o = cvt8((const float*)emb_raw + (size_t)idx[n] * 128 + q * 8);
  } else {
    o = *(const short8*)((const unsigned short*)emb_raw + (size_t)idx[n] * 128 + q * 8);
  }
  *(short8*)(feat + (size_t)tid * 8) = o;
}

__global__ void count_bs_kernel(const int* __restrict__ gid, float* __restrict__ cnt) {
  int g = threadIdx.x;  // 0..63
  int lo = 0, hi = N_NODES;
  while (lo < hi) { int m = (lo + hi) >> 1; if (gid[m] < g) lo = m + 1; else hi = m; }
  int a0 = lo; hi = N_NODES;
  while (lo < hi) { int m = (lo + hi) >> 1; if (gid[m] < g + 1) lo = m + 1; else hi = m; }
  cnt[g] = (float)(lo - a0);
}

__global__ void mean_sum_kernel(const bf16* __restrict__ feat, const int* __restrict__ gid,
                                float* __restrict__ gsum, int slot) {
  int n0 = blockIdx.x * 128;       // grid 391
  int h = threadIdx.x & 127;
  int r = threadIdx.x >> 7;
  float acc = 0.f; int curg = -1;
  for (int nn = r; nn < 128; nn += 2) {
    int node = n0 + nn;
    if (node >= N_NODES) break;
    int g = gid[node];
    if (g != curg) {
      if (curg >= 0) atomicAdd(&gsum[curg * 384 + slot * 128 + h], acc);
      curg = g; acc = 0.f;
    }
    acc += __bfloat162float(feat[(size_t)node * 128 + h]);
  }
  if (curg >= 0) atomicAdd(&gsum[curg * 384 + slot * 128 + h], acc);
}

// ---------- CSR build (parallel scan) ----------
__global__ void hist_kernel(const int* __restrict__ dst, int* __restrict__ deg) {
  int e = blockIdx.x * 256 + threadIdx.x;
  if (e < N_EDGES) atomicAdd(&deg[dst[e]], 1);
}
// per-chunk sums: 256 blocks x 256 threads
__global__ void csr_chunk_sum(const int* __restrict__ deg, int* __restrict__ csums) {
  __shared__ int sm[256];
  int b = blockIdx.x, t = threadIdx.x;
  int i = b * CHUNK + t;
  sm[t] = (t < CHUNK && i < N_NODES) ? deg[i] : 0;
  __syncthreads();
  for (int s = 128; s > 0; s >>= 1) { if (t < s) sm[t] += sm[t + s]; __syncthreads(); }
  if (t == 0) csums[b] = sm[0];
}
// 64-lane shfl scan of 256 chunk sums -> cbase
__global__ void csr_bases(const int* __restrict__ csums, int* __restrict__ cbase,
                          int* __restrict__ off) {
  int lane = threadIdx.x;  // 64
  int s0 = csums[lane * 4], s1 = csums[lane * 4 + 1];
  int s2 = csums[lane * 4 + 2], s3 = csums[lane * 4 + 3];
  int tot = s0 + s1 + s2 + s3;
  int sc = tot;
  for (int o = 1; o < 64; o <<= 1) { int u = __shfl_up(sc, o); if (lane >= o) sc += u; }
  int base = sc - tot;
  cbase[lane * 4] = base;
  cbase[lane * 4 + 1] = base + s0;
  cbase[lane * 4 + 2] = base + s0 + s1;
  cbase[lane * 4 + 3] = base + s0 + s1 + s2;
  if (lane == 63) off[N_NODES] = base + tot;  // == N_EDGES
}
// per-chunk exclusive scan -> off/cur: 256 blocks
__global__ void csr_write(const int* __restrict__ deg, const int* __restrict__ cbase,
                          int* __restrict__ off, int* __restrict__ cur) {
  __shared__ int A[256], B[256];
  int b = blockIdx.x, t = threadIdx.x;
  int i = b * CHUNK + t;
  int d = (t < CHUNK && i < N_NODES) ? deg[i] : 0;
  A[t] = d; __syncthreads();
  int* in = A; int* out = B;
  for (int s = 1; s < 256; s <<= 1) {
    out[t] = in[t] + ((t >= s) ? in[t - s] : 0);
    __syncthreads();
    int* tmp = in; in = out; out = tmp;
  }
  if (t < CHUNK && i < N_NODES) {
    int o = cbase[b] + in[t] - d;
    off[i] = o; cur[i] = o;
  }
}
__global__ void scatter_kernel(const int* __restrict__ src, const int* __restrict__ dst,
                               const int* __restrict__ et, int* __restrict__ cur,
                               int* __restrict__ val) {
  int e = blockIdx.x * 256 + threadIdx.x;
  if (e >= N_EDGES) return;
  int pos = atomicAdd(&cur[dst[e]], 1);
  val[pos] = src[e] | (et[e] << 16);   // src < 2^16, et < 4
}

// Wh3[e][n][128] = bf16( feat @ W_e + b_e ) for e=0..2, A-frags loaded once
__launch_bounds__(256)
__global__ void gemm_wh3_kernel(const bf16* __restrict__ A, const bf16* __restrict__ Bp,
                                const float* __restrict__ bias, bf16* __restrict__ C) {
  const int lane = threadIdx.x & 63;
  const int w = threadIdx.x >> 6;
  const int r0 = blockIdx.x * 64 + w * 16;
  int arow = r0 + (lane & 15);
  if (arow >= N_NODES) arow = N_NODES - 1;
  const int kb = (lane >> 4) << 3;
  short8 af[4];
#pragma unroll
  for (int kt = 0; kt < 4; ++kt)
    af[kt] = *(const short8*)(A + (size_t)arow * 128 + kt * 32 + kb);
  const int crow0 = r0 + ((lane >> 4) << 2);
  const int ccol = lane & 15;
  for (int e = 0; e < 3; ++e) {
    const bf16* Bpe = Bp + (size_t)e * 16384;
    const float* be = bias + e * 128;
    bf16* Ce = C + (size_t)e * N_NODES * 128;
#pragma unroll
    for (int nt = 0; nt < 8; ++nt) {
      f32x4 acc = {0.f, 0.f, 0.f, 0.f};
#pragma unroll
      for (int kt = 0; kt < 4; ++kt) {
        short8 bfr = *(const short8*)(Bpe + ((kt * 8 + nt) * 64 + lane) * 8);
        acc = __builtin_amdgcn_mfma_f32_16x16x32_bf16(af[kt], bfr, acc, 0, 0, 0);
      }
      float bv = be[nt * 16 + ccol];
#pragma unroll
      for (int rr = 0; rr < 4; ++rr) {
        int row = crow0 + rr;
        if (row < N_NODES) Ce[(size_t)row * 128 + nt * 16 + ccol] = __float2bfloat16(acc[rr] + bv);
      }
    }
  }
}

// one wave per dst: a[d] = sum of Wh3[ty][s] over in-edges (register accum, no atomics)
__launch_bounds__(256)
__global__ void edge_gather_kernel(const int* __restrict__ off, const int* __restrict__ val,
                                   const bf16* __restrict__ Wh3, bf16* __restrict__ a) {
  int d = blockIdx.x * 4 + (threadIdx.x >> 6);
  if (d >= N_NODES) return;
  int lane = threadIdx.x & 63;
  int e1 = off[d + 1];
  float a0 = 0.f, a1 = 0.f;
  for (int e = off[d]; e < e1; ++e) {
    int v = val[e];
    int s = v & 0xFFFF, ty = v >> 16;
    unsigned u = *(const unsigned*)(Wh3 + ((size_t)ty * N_NODES + s) * 128 + lane * 2);
    a0 += bfu((unsigned short)(u & 0xffff));
    a1 += bfu((unsigned short)(u >> 16));
  }
  unsigned o = ((unsigned)(unsigned short)bfbits(a1) << 16) | (unsigned short)bfbits(a0);
  *(unsigned*)(a + (size_t)d * 128 + lane * 2) = o;
}

// ---------- fallback small-ws path ----------
__launch_bounds__(256)
__global__ void gemm_wh1_kernel(const bf16* __restrict__ A, const bf16* __restrict__ Bp,
                                const float* __restrict__ bias, bf16* __restrict__ C) {
  const int lane = threadIdx.x & 63;
  const int w = threadIdx.x >> 6;
  const int r0 = blockIdx.x * 64 + w * 16;
  int arow = r0 + (lane & 15);
  if (arow >= N_NODES) arow = N_NODES - 1;
  const int kb = (lane >> 4) << 3;
  short8 af[4];
#pragma unroll
  for (int kt = 0; kt < 4; ++kt)
    af[kt] = *(const short8*)(A + (size_t)arow * 128 + kt * 32 + kb);
  const int crow0 = r0 + ((lane >> 4) << 2);
  const int ccol = lane & 15;
#pragma unroll
  for (int nt = 0; nt < 8; ++nt) {
    f32x4 acc = {0.f, 0.f, 0.f, 0.f};
#pragma unroll
    for (int kt = 0; kt < 4; ++kt) {
      short8 bfr = *(const short8*)(Bp + ((kt * 8 + nt) * 64 + lane) * 8);
      acc = __builtin_amdgcn_mfma_f32_16x16x32_bf16(af[kt], bfr, acc, 0, 0, 0);
    }
    float bv = bias[nt * 16 + ccol];
#pragma unroll
    for (int rr = 0; rr < 4; ++rr) {
      int row = crow0 + rr;
      if (row < N_NODES) C[(size_t)row * 128 + nt * 16 + ccol] = __float2bfloat16(acc[rr] + bv);
    }
  }
}
__global__ void edge_kernel(const int* __restrict__ src, const int* __restrict__ dst,
                            const int* __restrict__ et, const bf16* __restrict__ Wh,
                            float* __restrict__ a, int pass) {
  int e = blockIdx.x * 4 + (threadIdx.x >> 6);
  if (et[e] != pass) return;
  int lane = threadIdx.x & 63;
  int s = src[e], d = dst[e];
  unsigned u = *(const unsigned*)(Wh + (size_t)s * 128 + lane * 2);
  atomicAdd(&a[(size_t)d * 128 + lane * 2],     bfu((unsigned short)(u & 0xffff)));
  atomicAdd(&a[(size_t)d * 128 + lane * 2 + 1], bfu((unsigned short)(u >> 16)));
}
__global__ void cvt_a_kernel(const float* __restrict__ af, bf16* __restrict__ ab) {
  int i = blockIdx.x * 256 + threadIdx.x;  // 6.4M
  ab[i] = __float2bfloat16(af[i]);
}
// ----------------------------------------------------------

// Fused GRU: gi = a@Wih^T+bih, gh = feat@Whh^T+bhh, gate, feat(bf16) in-place. a is bf16.
__launch_bounds__(256)
__global__ void gru_kernel(const bf16* __restrict__ a, bf16* __restrict__ feat,
                           const bf16* __restrict__ Bih, const bf16* __restrict__ Bhh,
                           const float* __restrict__ bih, const float* __restrict__ bhh) {
  const int lane = threadIdx.x & 63;
  const int w = threadIdx.x >> 6;
  const int r0 = blockIdx.x * 64 + w * 16;
  int arow = r0 + (lane & 15);
  if (arow >= N_NODES) arow = N_NODES - 1;
  const int kb = (lane >> 4) << 3;
  short8 fa[4], fh[4];
#pragma unroll
  for (int kt = 0; kt < 4; ++kt) {
    fa[kt] = *(const short8*)(a + (size_t)arow * 128 + kt * 32 + kb);
    fh[kt] = *(const short8*)(feat + (size_t)arow * 128 + kt * 32 + kb);
  }
  const int crow0 = r0 + ((lane >> 4) << 2);
  const int ccol = lane & 15;
  f32x4 rg[8], zg[8];
#pragma unroll
  for (int g = 0; g < 3; ++g) {
#pragma unroll
    for (int nt = 0; nt < 8; ++nt) {
      const int ntg = g * 8 + nt;
      f32x4 gi = {0.f, 0.f, 0.f, 0.f}, gh = {0.f, 0.f, 0.f, 0.f};
#pragma unroll
      for (int kt = 0; kt < 4; ++kt) {
        short8 bi = *(const short8*)(Bih + ((size_t)(kt * 24 + ntg) * 64 + lane) * 8);
        short8 bh = *(const short8*)(Bhh + ((size_t)(kt * 24 + ntg) * 64 + lane) * 8);
        gi = __builtin_amdgcn_mfma_f32_16x16x32_bf16(fa[kt], bi, gi, 0, 0, 0);
        gh = __builtin_amdgcn_mfma_f32_16x16x32_bf16(fh[kt], bh, gh, 0, 0, 0);
      }
      float bvi = bih[ntg * 16 + ccol];
      float bvh = bhh[ntg * 16 + ccol];
      if (g == 0) {
#pragma unroll
        for (int rr = 0; rr < 4; ++rr)
          rg[nt][rr] = 1.f / (1.f + __expf(-(gi[rr] + bvi + gh[rr] + bvh)));
      } else if (g == 1) {
#pragma unroll
        for (int rr = 0; rr < 4; ++rr)
          zg[nt][rr] = 1.f / (1.f + __expf(-(gi[rr] + bvi + gh[rr] + bvh)));
      } else {
#pragma unroll
        for (int rr = 0; rr < 4; ++rr) {
          int row = crow0 + rr;
          if (row < N_NODES) {
            int col = nt * 16 + ccol;
            float hn = gh[rr] + bvh;
            float nc = tanhf(gi[rr] + bvi + rg[nt][rr] * hn);
            float hv = __bfloat162float(feat[(size_t)row * 128 + col]);
            float z = zg[nt][rr];
            feat[(size_t)row * 128 + col] = __float2bfloat16((1.f - z) * nc + z * hv);
          }
        }
      }
    }
  }
}

// OUTPUT IS FLOAT32 (reference returns jax f32 arrays).
__global__ void final_kernel(const float* __restrict__ gsum, const float* __restrict__ cnt,
                             const float* __restrict__ W1, const float* __restrict__ b1,
                             const float* __restrict__ W2, const float* __restrict__ b2,
                             float* __restrict__ out) {
  __shared__ float ga[384];
  __shared__ float red[2];
  int g = blockIdx.x, t = threadIdx.x;
  float c = fmaxf(cnt[g], 1.f);
  for (int k = t; k < 384; k += 128) {
    float m = gsum[g * 384 + k] / c;
    ga[k] = m;
    out[64 + g * 384 + k] = m;
  }
  __syncthreads();
  float acc = b1[t];
  for (int k = 0; k < 384; ++k) acc += ga[k] * W1[k * 128 + t];
  float x = fmaxf(acc, 0.f);
  float pv = x * W2[t];
#pragma unroll
  for (int off = 32; off > 0; off >>= 1) pv += __shfl_down(pv, off);
  if ((t & 63) == 0) red[t >> 6] = pv;
  __syncthreads();
  if (t == 0) out[g] = red[0] + red[1] + b2[0];
}

extern "C" void kernel_launch(void* const* d_in, const int* in_sizes, int n_in,
                              void* d_out, int out_size, void* d_ws, size_t ws_size,
                              hipStream_t stream) {
  const int* text_idx = (const int*)d_in[0];
  const int* srcp     = (const int*)d_in[1];
  const int* dstp     = (const int*)d_in[2];
  const int* etype    = (const int*)d_in[3];
  const int* gid      = (const int*)d_in[4];
  float* out = (float*)d_out;
  float* ws = (float*)d_ws;

  const bool big = ws_size >= (size_t)82000000;

  bf16 *feat, *abf, *Wh, *packWe;
  float *af32 = nullptr, *canon, *gsum;
  int *csr_off = nullptr, *csr_cur = nullptr, *csr_deg = nullptr, *csr_val = nullptr,
      *csr_csums = nullptr, *csr_cbase = nullptr;
  if (big) {
    feat   = (bf16*)ws;                      // [0, 3.2M) fl
    abf    = (bf16*)(ws + 3200000);          // [3.2M, 6.4M) fl
    Wh     = (bf16*)(ws + 6400000);          // [6.4M, 16.0M) fl  ([3][N][128] bf16)
    packWe = (bf16*)(ws + 16000000);
    canon  = ws + 16147456;
    gsum   = ws + 16494096;
    csr_off   = (int*)(ws + 16518744);       // 50001
    csr_cur   = csr_off + 50001;             // 50001
    csr_deg   = csr_cur + 50001;             // 50000
    csr_val   = csr_deg + 50000;             // 600000
    csr_csums = csr_val + 600000;            // 256
    csr_cbase = csr_csums + 256;             // 256
  } else {
    feat   = (bf16*)ws;
    af32   = ws + 3200000;
    Wh     = (bf16*)(ws + 9600000);
    packWe = (bf16*)(ws + 12800000);
    canon  = ws + 12947456;
    gsum   = ws + 13294096;
    abf    = Wh;
  }
  bf16* packWih = packWe + 98304;
  bf16* packWhh = packWih + 98304;
  float* cWl  = canon;
  float* cWih = canon + 98304;
  float* cWhh = canon + 196608;
  float* cbl  = canon + 294912;
  float* cbih = canon + 295680;
  float* cbhh = canon + 296448;
  float* cW1  = canon + 297216;
  float* cb1  = canon + 346368;
  float* cW2  = canon + 346496;
  float* cb2  = canon + 346624;
  float* cnt  = gsum + 24576;
  int*   fflag = (int*)(cnt + 64);

  detect_f_kernel<<<1, 64, 0, stream>>>((const unsigned short*)d_in[5], fflag);

  CvtArgs ca;
  ca.p[0] = d_in[6];  ca.p[1] = d_in[8];  ca.p[2] = d_in[9];  ca.p[3] = d_in[7];
  ca.p[4] = d_in[10]; ca.p[5] = d_in[11]; ca.p[6] = d_in[12]; ca.p[7] = d_in[13];
  ca.p[8] = d_in[14]; ca.p[9] = d_in[15];
  cvt_all_kernel<<<1355, 256, 0, stream>>>(ca, canon, fflag);

  hipMemsetAsync(gsum, 0, 24576 * sizeof(float), stream);
  pack_all_kernel<<<1152, 256, 0, stream>>>(cWl, cWih, cWhh, packWe, packWih, packWhh);

  if (big) {  // CSR once per launch (graph static across steps)
    hipMemsetAsync(csr_deg, 0, 50000 * sizeof(int), stream);
    hist_kernel<<<2344, 256, 0, stream>>>(dstp, csr_deg);
    csr_chunk_sum<<<256, 256, 0, stream>>>(csr_deg, csr_csums);
    csr_bases<<<1, 64, 0, stream>>>(csr_csums, csr_cbase, csr_off);
    csr_write<<<256, 256, 0, stream>>>(csr_deg, csr_cbase, csr_off, csr_cur);
    scatter_kernel<<<2344, 256, 0, stream>>>(srcp, dstp, etype, csr_cur, csr_val);
  }

  embed_v8_kernel<<<3125, 256, 0, stream>>>(text_idx, d_in[5], feat, fflag);
  count_bs_kernel<<<1, 64, 0, stream>>>(gid, cnt);
  mean_sum_kernel<<<391, 256, 0, stream>>>(feat, gid, gsum, 0);

  for (int l = 0; l < 2; ++l) {
    for (int s = 0; s < 2; ++s) {
      if (big) {
        gemm_wh3_kernel<<<782, 256, 0, stream>>>(feat, packWe + l * 3 * 16384,
                                                 cbl + l * 384, Wh);
        edge_gather_kernel<<<12500, 256, 0, stream>>>(csr_off, csr_val, Wh, abf);
      } else {
        hipMemsetAsync(af32, 0, 6400000 * sizeof(float), stream);
        for (int t = 0; t < 3; ++t) {
          gemm_wh1_kernel<<<782, 256, 0, stream>>>(feat, packWe + (l * 3 + t) * 16384,
                                                   cbl + l * 384 + t * 128, Wh);
          edge_kernel<<<150000, 256, 0, stream>>>(srcp, dstp, etype, Wh, af32, t);
        }
        cvt_a_kernel<<<25000, 256, 0, stream>>>(af32, abf);
      }
      gru_kernel<<<782, 256, 0, stream>>>(abf, feat, packWih + l * 49152, packWhh + l * 49152,
                                          cbih + l * 384, cbhh + l * 384);
    }
    mean_sum_kernel<<<391, 256, 0, stream>>>(feat, gid, gsum, l + 1);
  }

  final_kernel<<<64, 128, 0, stream>>>(gsum, cnt, cW1, cb1, cW2, cb2, out);
}

// Round 13
// 627.671 us; speedup vs baseline: 4.9960x; 1.4582x over previous
//
#include <hip/hip_runtime.h>
#include <hip/hip_bf16.h>

#define N_NODES 50000
#define N_EDGES 600000
#define N_GRAPHS 64
#define CHUNK 196  // 256*196 >= 50000

typedef __hip_bfloat16 bf16;
typedef __attribute__((ext_vector_type(8))) short short8;
typedef __attribute__((ext_vector_type(4))) float f32x4;

static __device__ inline short bfbits(float x) {
  union { bf16 h; short s; } u;
  u.h = __float2bfloat16(x);
  return u.s;
}
static __device__ inline float bfu(unsigned short s) {
  union { float f; unsigned u; } x; x.u = ((unsigned)s) << 16; return x.f;
}
static __device__ inline short8 cvt8(const float* p) {
  f32x4 v0 = *(const f32x4*)p, v1 = *(const f32x4*)(p + 4);
  short8 r;
  r[0] = bfbits(v0[0]); r[1] = bfbits(v0[1]); r[2] = bfbits(v0[2]); r[3] = bfbits(v0[3]);
  r[4] = bfbits(v1[0]); r[5] = bfbits(v1[1]); r[6] = bfbits(v1[2]); r[7] = bfbits(v1[3]);
  return r;
}

// float dtype detection: bf16 (flag=0) or float32 (flag=1)?  (R5 verified: f32)
__global__ void detect_f_kernel(const unsigned short* __restrict__ raw, int* __restrict__ flag) {
  int t = threadIdx.x;  // 64
  int wild = 0;
  for (int i = 0; i < 4; ++i) {
    unsigned short u = raw[t * 4 + i];
    int e = (u >> 7) & 0xFF;
    if (u != 0 && (e < 96 || e > 159)) wild++;
  }
#pragma unroll
  for (int off = 32; off > 0; off >>= 1) wild += __shfl_down(wild, off);
  if (t == 0) *flag = (wild >= 32) ? 1 : 0;
}

// all 10 small float params -> canon, one launch
struct CvtArgs { const void* p[10]; };
__global__ void cvt_all_kernel(CvtArgs args, float* __restrict__ canon,
                               const int* __restrict__ flag) {
  int i = blockIdx.x * 256 + threadIdx.x;
  if (i >= 346625) return;
  const int offs[11] = {0, 98304, 196608, 294912, 295680, 296448,
                        297216, 346368, 346496, 346624, 346625};
  int seg = 0;
#pragma unroll
  for (int k = 1; k < 10; ++k) if (i >= offs[k]) seg = k;
  int j = i - offs[seg];
  const void* s = args.p[seg];
  canon[i] = (*flag) ? ((const float*)s)[j] : bfu(((const unsigned short*)s)[j]);
}

// all weight packs in one launch (294,912 elements)
__global__ void pack_all_kernel(const float* __restrict__ cWl, const float* __restrict__ cWih,
                                const float* __restrict__ cWhh, bf16* __restrict__ packWe,
                                bf16* __restrict__ packWih, bf16* __restrict__ packWhh) {
  int tid = blockIdx.x * 256 + threadIdx.x;
  if (tid >= 294912) return;
  const float* src; bf16* dst; int NN, transpose, within;
  if (tid < 98304) {
    int m = tid >> 14; within = tid & 16383;
    src = cWl + m * 16384; dst = packWe + m * 16384; NN = 128; transpose = 0;
  } else if (tid < 196608) {
    int t2 = tid - 98304; int l = t2 / 49152; within = t2 % 49152;
    src = cWih + l * 49152; dst = packWih + l * 49152; NN = 384; transpose = 1;
  } else {
    int t2 = tid - 196608; int l = t2 / 49152; within = t2 % 49152;
    src = cWhh + l * 49152; dst = packWhh + l * 49152; NN = 384; transpose = 1;
  }
  int NT = NN >> 4;
  int i = within & 7;
  int lane = (within >> 3) & 63;
  int rest = within >> 9;
  int nt = rest % NT, kt = rest / NT;
  int k = kt * 32 + ((lane >> 4) << 3) + i;
  int n = nt * 16 + (lane & 15);
  dst[within] = __float2bfloat16(transpose ? src[n * 128 + k] : src[k * NN + n]);
}

__global__ void embed_v8_kernel(const int* __restrict__ idx, const void* __restrict__ emb_raw,
                                bf16* __restrict__ feat, const int* __restrict__ flag) {
  int tid = blockIdx.x * 256 + threadIdx.x;  // 800,000 exactly
  int n = tid >> 4, q = tid & 15;
  short8 o;
  if (*flag) {
    o = cvt8((const float*)emb_raw + (size_t)idx[n] * 128 + q * 8);
  } else {
    o = *(const short8*)((const unsigned short*)emb_raw + (size_t)idx[n] * 128 + q * 8);
  }
  *(short8*)(feat + (size_t)tid * 8) = o;
}

__global__ void count_bs_kernel(const int* __restrict__ gid, float* __restrict__ cnt) {
  int g = threadIdx.x;  // 0..63
  int lo = 0, hi = N_NODES;
  while (lo < hi) { int m = (lo + hi) >> 1; if (gid[m] < g) lo = m + 1; else hi = m; }
  int a0 = lo; hi = N_NODES;
  while (lo < hi) { int m = (lo + hi) >> 1; if (gid[m] < g + 1) lo = m + 1; else hi = m; }
  cnt[g] = (float)(lo - a0);
}

__global__ void mean_sum_kernel(const bf16* __restrict__ feat, const int* __restrict__ gid,
                                float* __restrict__ gsum, int slot) {
  int n0 = blockIdx.x * 128;       // grid 391
  int h = threadIdx.x & 127;
  int r = threadIdx.x >> 7;
  float acc = 0.f; int curg = -1;
  for (int nn = r; nn < 128; nn += 2) {
    int node = n0 + nn;
    if (node >= N_NODES) break;
    int g = gid[node];
    if (g != curg) {
      if (curg >= 0) atomicAdd(&gsum[curg * 384 + slot * 128 + h], acc);
      curg = g; acc = 0.f;
    }
    acc += __bfloat162float(feat[(size_t)node * 128 + h]);
  }
  if (curg >= 0) atomicAdd(&gsum[curg * 384 + slot * 128 + h], acc);
}

// ---------- CSR build (parallel scan) ----------
__global__ void hist_kernel(const int* __restrict__ dst, int* __restrict__ deg) {
  int e = blockIdx.x * 256 + threadIdx.x;
  if (e < N_EDGES) atomicAdd(&deg[dst[e]], 1);
}
__global__ void csr_chunk_sum(const int* __restrict__ deg, int* __restrict__ csums) {
  __shared__ int sm[256];
  int b = blockIdx.x, t = threadIdx.x;
  int i = b * CHUNK + t;
  sm[t] = (t < CHUNK && i < N_NODES) ? deg[i] : 0;
  __syncthreads();
  for (int s = 128; s > 0; s >>= 1) { if (t < s) sm[t] += sm[t + s]; __syncthreads(); }
  if (t == 0) csums[b] = sm[0];
}
__global__ void csr_bases(const int* __restrict__ csums, int* __restrict__ cbase,
                          int* __restrict__ off) {
  int lane = threadIdx.x;  // 64
  int s0 = csums[lane * 4], s1 = csums[lane * 4 + 1];
  int s2 = csums[lane * 4 + 2], s3 = csums[lane * 4 + 3];
  int tot = s0 + s1 + s2 + s3;
  int sc = tot;
  for (int o = 1; o < 64; o <<= 1) { int u = __shfl_up(sc, o); if (lane >= o) sc += u; }
  int base = sc - tot;
  cbase[lane * 4] = base;
  cbase[lane * 4 + 1] = base + s0;
  cbase[lane * 4 + 2] = base + s0 + s1;
  cbase[lane * 4 + 3] = base + s0 + s1 + s2;
  if (lane == 63) off[N_NODES] = base + tot;
}
__global__ void csr_write(const int* __restrict__ deg, const int* __restrict__ cbase,
                          int* __restrict__ off, int* __restrict__ cur) {
  __shared__ int A[256], B[256];
  int b = blockIdx.x, t = threadIdx.x;
  int i = b * CHUNK + t;
  int d = (t < CHUNK && i < N_NODES) ? deg[i] : 0;
  A[t] = d; __syncthreads();
  int* in = A; int* out = B;
  for (int s = 1; s < 256; s <<= 1) {
    out[t] = in[t] + ((t >= s) ? in[t - s] : 0);
    __syncthreads();
    int* tmp = in; in = out; out = tmp;
  }
  if (t < CHUNK && i < N_NODES) {
    int o = cbase[b] + in[t] - d;
    off[i] = o; cur[i] = o;
  }
}
__global__ void scatter_kernel(const int* __restrict__ src, const int* __restrict__ dst,
                               const int* __restrict__ et, int* __restrict__ cur,
                               int* __restrict__ val) {
  int e = blockIdx.x * 256 + threadIdx.x;
  if (e >= N_EDGES) return;
  int pos = atomicAdd(&cur[dst[e]], 1);
  val[pos] = src[e] | (et[e] << 16);
}

// Wh3[e][n][128] = bf16( feat @ W_e + b_e ) for e=0..2, A-frags loaded once
__launch_bounds__(256)
__global__ void gemm_wh3_kernel(const bf16* __restrict__ A, const bf16* __restrict__ Bp,
                                const float* __restrict__ bias, bf16* __restrict__ C) {
  const int lane = threadIdx.x & 63;
  const int w = threadIdx.x >> 6;
  const int r0 = blockIdx.x * 64 + w * 16;
  int arow = r0 + (lane & 15);
  if (arow >= N_NODES) arow = N_NODES - 1;
  const int kb = (lane >> 4) << 3;
  short8 af[4];
#pragma unroll
  for (int kt = 0; kt < 4; ++kt)
    af[kt] = *(const short8*)(A + (size_t)arow * 128 + kt * 32 + kb);
  const int crow0 = r0 + ((lane >> 4) << 2);
  const int ccol = lane & 15;
  for (int e = 0; e < 3; ++e) {
    const bf16* Bpe = Bp + (size_t)e * 16384;
    const float* be = bias + e * 128;
    bf16* Ce = C + (size_t)e * N_NODES * 128;
#pragma unroll
    for (int nt = 0; nt < 8; ++nt) {
      f32x4 acc = {0.f, 0.f, 0.f, 0.f};
#pragma unroll
      for (int kt = 0; kt < 4; ++kt) {
        short8 bfr = *(const short8*)(Bpe + ((kt * 8 + nt) * 64 + lane) * 8);
        acc = __builtin_amdgcn_mfma_f32_16x16x32_bf16(af[kt], bfr, acc, 0, 0, 0);
      }
      float bv = be[nt * 16 + ccol];
#pragma unroll
      for (int rr = 0; rr < 4; ++rr) {
        int row = crow0 + rr;
        if (row < N_NODES) Ce[(size_t)row * 128 + nt * 16 + ccol] = __float2bfloat16(acc[rr] + bv);
      }
    }
  }
}

// one wave per dst: lane-preloaded edge list + shfl broadcast, 2-way unrolled gather
__launch_bounds__(256)
__global__ void edge_gather_kernel(const int* __restrict__ off, const int* __restrict__ val,
                                   const bf16* __restrict__ Wh3, bf16* __restrict__ a) {
  int d = blockIdx.x * 4 + (threadIdx.x >> 6);
  if (d >= N_NODES) return;
  int lane = threadIdx.x & 63;
  int e0 = off[d];
  int deg = off[d + 1] - e0;
  float a0 = 0.f, a1 = 0.f, b0 = 0.f, b1 = 0.f;
  for (int base = 0; base < deg; base += 64) {
    int rem = deg - base; if (rem > 64) rem = 64;
    int v = (lane < rem) ? val[e0 + base + lane] : 0;
    int j = 0;
    for (; j + 2 <= rem; j += 2) {
      int v0 = __shfl(v, j), v1 = __shfl(v, j + 1);
      unsigned u0 = *(const unsigned*)(Wh3 +
                      ((size_t)(v0 >> 16) * N_NODES + (v0 & 0xFFFF)) * 128 + lane * 2);
      unsigned u1 = *(const unsigned*)(Wh3 +
                      ((size_t)(v1 >> 16) * N_NODES + (v1 & 0xFFFF)) * 128 + lane * 2);
      a0 += bfu((unsigned short)(u0 & 0xffff)); a1 += bfu((unsigned short)(u0 >> 16));
      b0 += bfu((unsigned short)(u1 & 0xffff)); b1 += bfu((unsigned short)(u1 >> 16));
    }
    if (j < rem) {
      int v0 = __shfl(v, j);
      unsigned u0 = *(const unsigned*)(Wh3 +
                      ((size_t)(v0 >> 16) * N_NODES + (v0 & 0xFFFF)) * 128 + lane * 2);
      a0 += bfu((unsigned short)(u0 & 0xffff)); a1 += bfu((unsigned short)(u0 >> 16));
    }
  }
  a0 += b0; a1 += b1;
  unsigned o = ((unsigned)(unsigned short)bfbits(a1) << 16) | (unsigned short)bfbits(a0);
  *(unsigned*)(a + (size_t)d * 128 + lane * 2) = o;
}

// ---------- fallback small-ws path ----------
__launch_bounds__(256)
__global__ void gemm_wh1_kernel(const bf16* __restrict__ A, const bf16* __restrict__ Bp,
                                const float* __restrict__ bias, bf16* __restrict__ C) {
  const int lane = threadIdx.x & 63;
  const int w = threadIdx.x >> 6;
  const int r0 = blockIdx.x * 64 + w * 16;
  int arow = r0 + (lane & 15);
  if (arow >= N_NODES) arow = N_NODES - 1;
  const int kb = (lane >> 4) << 3;
  short8 af[4];
#pragma unroll
  for (int kt = 0; kt < 4; ++kt)
    af[kt] = *(const short8*)(A + (size_t)arow * 128 + kt * 32 + kb);
  const int crow0 = r0 + ((lane >> 4) << 2);
  const int ccol = lane & 15;
#pragma unroll
  for (int nt = 0; nt < 8; ++nt) {
    f32x4 acc = {0.f, 0.f, 0.f, 0.f};
#pragma unroll
    for (int kt = 0; kt < 4; ++kt) {
      short8 bfr = *(const short8*)(Bp + ((kt * 8 + nt) * 64 + lane) * 8);
      acc = __builtin_amdgcn_mfma_f32_16x16x32_bf16(af[kt], bfr, acc, 0, 0, 0);
    }
    float bv = bias[nt * 16 + ccol];
#pragma unroll
    for (int rr = 0; rr < 4; ++rr) {
      int row = crow0 + rr;
      if (row < N_NODES) C[(size_t)row * 128 + nt * 16 + ccol] = __float2bfloat16(acc[rr] + bv);
    }
  }
}
__global__ void edge_kernel(const int* __restrict__ src, const int* __restrict__ dst,
                            const int* __restrict__ et, const bf16* __restrict__ Wh,
                            float* __restrict__ a, int pass) {
  int e = blockIdx.x * 4 + (threadIdx.x >> 6);
  if (et[e] != pass) return;
  int lane = threadIdx.x & 63;
  int s = src[e], d = dst[e];
  unsigned u = *(const unsigned*)(Wh + (size_t)s * 128 + lane * 2);
  atomicAdd(&a[(size_t)d * 128 + lane * 2],     bfu((unsigned short)(u & 0xffff)));
  atomicAdd(&a[(size_t)d * 128 + lane * 2 + 1], bfu((unsigned short)(u >> 16)));
}
__global__ void cvt_a_kernel(const float* __restrict__ af, bf16* __restrict__ ab) {
  int i = blockIdx.x * 256 + threadIdx.x;  // 6.4M
  ab[i] = __float2bfloat16(af[i]);
}
// ----------------------------------------------------------

// Fused GRU, nt-outer loop: all 3 gates per nt, gate+write immediately.
// VGPR target <=128 for 4 waves/SIMD.
__launch_bounds__(256, 4)
__global__ void gru_kernel(const bf16* __restrict__ a, bf16* __restrict__ feat,
                           const bf16* __restrict__ Bih, const bf16* __restrict__ Bhh,
                           const float* __restrict__ bih, const float* __restrict__ bhh) {
  const int lane = threadIdx.x & 63;
  const int w = threadIdx.x >> 6;
  const int r0 = blockIdx.x * 64 + w * 16;
  int arow = r0 + (lane & 15);
  if (arow >= N_NODES) arow = N_NODES - 1;
  const int kb = (lane >> 4) << 3;
  short8 fa[4], fh[4];
#pragma unroll
  for (int kt = 0; kt < 4; ++kt) {
    fa[kt] = *(const short8*)(a + (size_t)arow * 128 + kt * 32 + kb);
    fh[kt] = *(const short8*)(feat + (size_t)arow * 128 + kt * 32 + kb);
  }
  const int crow0 = r0 + ((lane >> 4) << 2);
  const int ccol = lane & 15;
#pragma unroll
  for (int nt = 0; nt < 8; ++nt) {
    f32x4 gi[3], gh[3];
#pragma unroll
    for (int g = 0; g < 3; ++g) { gi[g] = {0.f, 0.f, 0.f, 0.f}; gh[g] = {0.f, 0.f, 0.f, 0.f}; }
#pragma unroll
    for (int g = 0; g < 3; ++g) {
      const int ntg = g * 8 + nt;
#pragma unroll
      for (int kt = 0; kt < 4; ++kt) {
        short8 bi = *(const short8*)(Bih + ((size_t)(kt * 24 + ntg) * 64 + lane) * 8);
        short8 bh = *(const short8*)(Bhh + ((size_t)(kt * 24 + ntg) * 64 + lane) * 8);
        gi[g] = __builtin_amdgcn_mfma_f32_16x16x32_bf16(fa[kt], bi, gi[g], 0, 0, 0);
        gh[g] = __builtin_amdgcn_mfma_f32_16x16x32_bf16(fh[kt], bh, gh[g], 0, 0, 0);
      }
    }
    float bvi0 = bih[(0 * 8 + nt) * 16 + ccol], bvh0 = bhh[(0 * 8 + nt) * 16 + ccol];
    float bvi1 = bih[(1 * 8 + nt) * 16 + ccol], bvh1 = bhh[(1 * 8 + nt) * 16 + ccol];
    float bvi2 = bih[(2 * 8 + nt) * 16 + ccol], bvh2 = bhh[(2 * 8 + nt) * 16 + ccol];
#pragma unroll
    for (int rr = 0; rr < 4; ++rr) {
      int row = crow0 + rr;
      if (row < N_NODES) {
        int col = nt * 16 + ccol;
        float rg = 1.f / (1.f + __expf(-(gi[0][rr] + bvi0 + gh[0][rr] + bvh0)));
        float zg = 1.f / (1.f + __expf(-(gi[1][rr] + bvi1 + gh[1][rr] + bvh1)));
        float hn = gh[2][rr] + bvh2;
        float nc = tanhf(gi[2][rr] + bvi2 + rg * hn);
        float hv = __bfloat162float(feat[(size_t)row * 128 + col]);
        feat[(size_t)row * 128 + col] = __float2bfloat16((1.f - zg) * nc + zg * hv);
      }
    }
  }
}

// OUTPUT IS FLOAT32 (reference returns jax f32 arrays).
__global__ void final_kernel(const float* __restrict__ gsum, const float* __restrict__ cnt,
                             const float* __restrict__ W1, const float* __restrict__ b1,
                             const float* __restrict__ W2, const float* __restrict__ b2,
                             float* __restrict__ out) {
  __shared__ float ga[384];
  __shared__ float red[2];
  int g = blockIdx.x, t = threadIdx.x;
  float c = fmaxf(cnt[g], 1.f);
  for (int k = t; k < 384; k += 128) {
    float m = gsum[g * 384 + k] / c;
    ga[k] = m;
    out[64 + g * 384 + k] = m;
  }
  __syncthreads();
  float acc = b1[t];
  for (int k = 0; k < 384; ++k) acc += ga[k] * W1[k * 128 + t];
  float x = fmaxf(acc, 0.f);
  float pv = x * W2[t];
#pragma unroll
  for (int off = 32; off > 0; off >>= 1) pv += __shfl_down(pv, off);
  if ((t & 63) == 0) red[t >> 6] = pv;
  __syncthreads();
  if (t == 0) out[g] = red[0] + red[1] + b2[0];
}

extern "C" void kernel_launch(void* const* d_in, const int* in_sizes, int n_in,
                              void* d_out, int out_size, void* d_ws, size_t ws_size,
                              hipStream_t stream) {
  const int* text_idx = (const int*)d_in[0];
  const int* srcp     = (const int*)d_in[1];
  const int* dstp     = (const int*)d_in[2];
  const int* etype    = (const int*)d_in[3];
  const int* gid      = (const int*)d_in[4];
  float* out = (float*)d_out;
  float* ws = (float*)d_ws;

  const bool big = ws_size >= (size_t)82000000;

  bf16 *feat, *abf, *Wh, *packWe;
  float *af32 = nullptr, *canon, *gsum;
  int *csr_off = nullptr, *csr_cur = nullptr, *csr_deg = nullptr, *csr_val = nullptr,
      *csr_csums = nullptr, *csr_cbase = nullptr;
  if (big) {
    feat   = (bf16*)ws;
    abf    = (bf16*)(ws + 3200000);
    Wh     = (bf16*)(ws + 6400000);
    packWe = (bf16*)(ws + 16000000);
    canon  = ws + 16147456;
    gsum   = ws + 16494096;
    csr_off   = (int*)(ws + 16518744);
    csr_cur   = csr_off + 50001;
    csr_deg   = csr_cur + 50001;
    csr_val   = csr_deg + 50000;
    csr_csums = csr_val + 600000;
    csr_cbase = csr_csums + 256;
  } else {
    feat   = (bf16*)ws;
    af32   = ws + 3200000;
    Wh     = (bf16*)(ws + 9600000);
    packWe = (bf16*)(ws + 12800000);
    canon  = ws + 12947456;
    gsum   = ws + 13294096;
    abf    = Wh;
  }
  bf16* packWih = packWe + 98304;
  bf16* packWhh = packWih + 98304;
  float* cWl  = canon;
  float* cWih = canon + 98304;
  float* cWhh = canon + 196608;
  float* cbl  = canon + 294912;
  float* cbih = canon + 295680;
  float* cbhh = canon + 296448;
  float* cW1  = canon + 297216;
  float* cb1  = canon + 346368;
  float* cW2  = canon + 346496;
  float* cb2  = canon + 346624;
  float* cnt  = gsum + 24576;
  int*   fflag = (int*)(cnt + 64);

  detect_f_kernel<<<1, 64, 0, stream>>>((const unsigned short*)d_in[5], fflag);

  CvtArgs ca;
  ca.p[0] = d_in[6];  ca.p[1] = d_in[8];  ca.p[2] = d_in[9];  ca.p[3] = d_in[7];
  ca.p[4] = d_in[10]; ca.p[5] = d_in[11]; ca.p[6] = d_in[12]; ca.p[7] = d_in[13];
  ca.p[8] = d_in[14]; ca.p[9] = d_in[15];
  cvt_all_kernel<<<1355, 256, 0, stream>>>(ca, canon, fflag);

  hipMemsetAsync(gsum, 0, 24576 * sizeof(float), stream);
  pack_all_kernel<<<1152, 256, 0, stream>>>(cWl, cWih, cWhh, packWe, packWih, packWhh);

  if (big) {
    hipMemsetAsync(csr_deg, 0, 50000 * sizeof(int), stream);
    hist_kernel<<<2344, 256, 0, stream>>>(dstp, csr_deg);
    csr_chunk_sum<<<256, 256, 0, stream>>>(csr_deg, csr_csums);
    csr_bases<<<1, 64, 0, stream>>>(csr_csums, csr_cbase, csr_off);
    csr_write<<<256, 256, 0, stream>>>(csr_deg, csr_cbase, csr_off, csr_cur);
    scatter_kernel<<<2344, 256, 0, stream>>>(srcp, dstp, etype, csr_cur, csr_val);
  }

  embed_v8_kernel<<<3125, 256, 0, stream>>>(text_idx, d_in[5], feat, fflag);
  count_bs_kernel<<<1, 64, 0, stream>>>(gid, cnt);
  mean_sum_kernel<<<391, 256, 0, stream>>>(feat, gid, gsum, 0);

  for (int l = 0; l < 2; ++l) {
    for (int s = 0; s < 2; ++s) {
      if (big) {
        gemm_wh3_kernel<<<782, 256, 0, stream>>>(feat, packWe + l * 3 * 16384,
                                                 cbl + l * 384, Wh);
        edge_gather_kernel<<<12500, 256, 0, stream>>>(csr_off, csr_val, Wh, abf);
      } else {
        hipMemsetAsync(af32, 0, 6400000 * sizeof(float), stream);
        for (int t = 0; t < 3; ++t) {
          gemm_wh1_kernel<<<782, 256, 0, stream>>>(feat, packWe + (l * 3 + t) * 16384,
                                                   cbl + l * 384 + t * 128, Wh);
          edge_kernel<<<150000, 256, 0, stream>>>(srcp, dstp, etype, Wh, af32, t);
        }
        cvt_a_kernel<<<25000, 256, 0, stream>>>(af32, abf);
      }
      gru_kernel<<<782, 256, 0, stream>>>(abf, feat, packWih + l * 49152, packWhh + l * 49152,
                                          cbih + l * 384, cbhh + l * 384);
    }
    mean_sum_kernel<<<391, 256, 0, stream>>>(feat, gid, gsum, l + 1);
  }

  final_kernel<<<64, 128, 0, stream>>>(gsum, cnt, cW1, cb1, cW2, cb2, out);
}

// Round 14
// 544.254 us; speedup vs baseline: 5.7617x; 1.1533x over previous
//
#include <hip/hip_runtime.h>
#include <hip/hip_bf16.h>

#define N_NODES 50000
#define N_EDGES 600000
#define N_GRAPHS 64
#define CHUNK 196  // 256*196 >= 50000

typedef __hip_bfloat16 bf16;
typedef __attribute__((ext_vector_type(8))) short short8;
typedef __attribute__((ext_vector_type(4))) float f32x4;

static __device__ inline short bfbits(float x) {
  union { bf16 h; short s; } u;
  u.h = __float2bfloat16(x);
  return u.s;
}
static __device__ inline float bfu(unsigned short s) {
  union { float f; unsigned u; } x; x.u = ((unsigned)s) << 16; return x.f;
}
static __device__ inline short8 cvt8(const float* p) {
  f32x4 v0 = *(const f32x4*)p, v1 = *(const f32x4*)(p + 4);
  short8 r;
  r[0] = bfbits(v0[0]); r[1] = bfbits(v0[1]); r[2] = bfbits(v0[2]); r[3] = bfbits(v0[3]);
  r[4] = bfbits(v1[0]); r[5] = bfbits(v1[1]); r[6] = bfbits(v1[2]); r[7] = bfbits(v1[3]);
  return r;
}

// float dtype detection: bf16 (flag=0) or float32 (flag=1)?  (R5 verified: f32)
__global__ void detect_f_kernel(const unsigned short* __restrict__ raw, int* __restrict__ flag) {
  int t = threadIdx.x;  // 64
  int wild = 0;
  for (int i = 0; i < 4; ++i) {
    unsigned short u = raw[t * 4 + i];
    int e = (u >> 7) & 0xFF;
    if (u != 0 && (e < 96 || e > 159)) wild++;
  }
#pragma unroll
  for (int off = 32; off > 0; off >>= 1) wild += __shfl_down(wild, off);
  if (t == 0) *flag = (wild >= 32) ? 1 : 0;
}

// all 10 small float params -> canon, one launch
struct CvtArgs { const void* p[10]; };
__global__ void cvt_all_kernel(CvtArgs args, float* __restrict__ canon,
                               const int* __restrict__ flag) {
  int i = blockIdx.x * 256 + threadIdx.x;
  if (i >= 346625) return;
  const int offs[11] = {0, 98304, 196608, 294912, 295680, 296448,
                        297216, 346368, 346496, 346624, 346625};
  int seg = 0;
#pragma unroll
  for (int k = 1; k < 10; ++k) if (i >= offs[k]) seg = k;
  int j = i - offs[seg];
  const void* s = args.p[seg];
  canon[i] = (*flag) ? ((const float*)s)[j] : bfu(((const unsigned short*)s)[j]);
}

// all weight packs in one launch (294,912 elements)
__global__ void pack_all_kernel(const float* __restrict__ cWl, const float* __restrict__ cWih,
                                const float* __restrict__ cWhh, bf16* __restrict__ packWe,
                                bf16* __restrict__ packWih, bf16* __restrict__ packWhh) {
  int tid = blockIdx.x * 256 + threadIdx.x;
  if (tid >= 294912) return;
  const float* src; bf16* dst; int NN, transpose, within;
  if (tid < 98304) {
    int m = tid >> 14; within = tid & 16383;
    src = cWl + m * 16384; dst = packWe + m * 16384; NN = 128; transpose = 0;
  } else if (tid < 196608) {
    int t2 = tid - 98304; int l = t2 / 49152; within = t2 % 49152;
    src = cWih + l * 49152; dst = packWih + l * 49152; NN = 384; transpose = 1;
  } else {
    int t2 = tid - 196608; int l = t2 / 49152; within = t2 % 49152;
    src = cWhh + l * 49152; dst = packWhh + l * 49152; NN = 384; transpose = 1;
  }
  int NT = NN >> 4;
  int i = within & 7;
  int lane = (within >> 3) & 63;
  int rest = within >> 9;
  int nt = rest % NT, kt = rest / NT;
  int k = kt * 32 + ((lane >> 4) << 3) + i;
  int n = nt * 16 + (lane & 15);
  dst[within] = __float2bfloat16(transpose ? src[n * 128 + k] : src[k * NN + n]);
}

__global__ void embed_v8_kernel(const int* __restrict__ idx, const void* __restrict__ emb_raw,
                                bf16* __restrict__ feat, const int* __restrict__ flag) {
  int tid = blockIdx.x * 256 + threadIdx.x;  // 800,000 exactly
  int n = tid >> 4, q = tid & 15;
  short8 o;
  if (*flag) {
    o = cvt8((const float*)emb_raw + (size_t)idx[n] * 128 + q * 8);
  } else {
    o = *(const short8*)((const unsigned short*)emb_raw + (size_t)idx[n] * 128 + q * 8);
  }
  *(short8*)(feat + (size_t)tid * 8) = o;
}

__global__ void count_bs_kernel(const int* __restrict__ gid, float* __restrict__ cnt) {
  int g = threadIdx.x;  // 0..63
  int lo = 0, hi = N_NODES;
  while (lo < hi) { int m = (lo + hi) >> 1; if (gid[m] < g) lo = m + 1; else hi = m; }
  int a0 = lo; hi = N_NODES;
  while (lo < hi) { int m = (lo + hi) >> 1; if (gid[m] < g + 1) lo = m + 1; else hi = m; }
  cnt[g] = (float)(lo - a0);
}

__global__ void mean_sum_kernel(const bf16* __restrict__ feat, const int* __restrict__ gid,
                                float* __restrict__ gsum, int slot) {
  int n0 = blockIdx.x * 64;        // grid 782
  int h = threadIdx.x & 127;
  int r = threadIdx.x >> 7;
  float acc = 0.f; int curg = -1;
  for (int nn = r; nn < 64; nn += 2) {
    int node = n0 + nn;
    if (node >= N_NODES) break;
    int g = gid[node];
    if (g != curg) {
      if (curg >= 0) atomicAdd(&gsum[curg * 384 + slot * 128 + h], acc);
      curg = g; acc = 0.f;
    }
    acc += __bfloat162float(feat[(size_t)node * 128 + h]);
  }
  if (curg >= 0) atomicAdd(&gsum[curg * 384 + slot * 128 + h], acc);
}

// ---------- CSR build (parallel scan) ----------
__global__ void hist_kernel(const int* __restrict__ dst, int* __restrict__ deg) {
  int e = blockIdx.x * 256 + threadIdx.x;
  if (e < N_EDGES) atomicAdd(&deg[dst[e]], 1);
}
__global__ void csr_chunk_sum(const int* __restrict__ deg, int* __restrict__ csums) {
  __shared__ int sm[256];
  int b = blockIdx.x, t = threadIdx.x;
  int i = b * CHUNK + t;
  sm[t] = (t < CHUNK && i < N_NODES) ? deg[i] : 0;
  __syncthreads();
  for (int s = 128; s > 0; s >>= 1) { if (t < s) sm[t] += sm[t + s]; __syncthreads(); }
  if (t == 0) csums[b] = sm[0];
}
__global__ void csr_bases(const int* __restrict__ csums, int* __restrict__ cbase,
                          int* __restrict__ off) {
  int lane = threadIdx.x;  // 64
  int s0 = csums[lane * 4], s1 = csums[lane * 4 + 1];
  int s2 = csums[lane * 4 + 2], s3 = csums[lane * 4 + 3];
  int tot = s0 + s1 + s2 + s3;
  int sc = tot;
  for (int o = 1; o < 64; o <<= 1) { int u = __shfl_up(sc, o); if (lane >= o) sc += u; }
  int base = sc - tot;
  cbase[lane * 4] = base;
  cbase[lane * 4 + 1] = base + s0;
  cbase[lane * 4 + 2] = base + s0 + s1;
  cbase[lane * 4 + 3] = base + s0 + s1 + s2;
  if (lane == 63) off[N_NODES] = base + tot;
}
__global__ void csr_write(const int* __restrict__ deg, const int* __restrict__ cbase,
                          int* __restrict__ off, int* __restrict__ cur) {
  __shared__ int A[256], B[256];
  int b = blockIdx.x, t = threadIdx.x;
  int i = b * CHUNK + t;
  int d = (t < CHUNK && i < N_NODES) ? deg[i] : 0;
  A[t] = d; __syncthreads();
  int* in = A; int* out = B;
  for (int s = 1; s < 256; s <<= 1) {
    out[t] = in[t] + ((t >= s) ? in[t - s] : 0);
    __syncthreads();
    int* tmp = in; in = out; out = tmp;
  }
  if (t < CHUNK && i < N_NODES) {
    int o = cbase[b] + in[t] - d;
    off[i] = o; cur[i] = o;
  }
}
__global__ void scatter_kernel(const int* __restrict__ src, const int* __restrict__ dst,
                               const int* __restrict__ et, int* __restrict__ cur,
                               int* __restrict__ val) {
  int e = blockIdx.x * 256 + threadIdx.x;
  if (e >= N_EDGES) return;
  int pos = atomicAdd(&cur[dst[e]], 1);
  val[pos] = src[e] | (et[e] << 16);
}

// Wh3[e][n][128] = bf16( feat @ W_e + b_e ), nt split across waves:
// wave = (rowgrp = w&1, nthalf = w>>1); 16 rows x 4 nt x 3 e per wave. grid 1563.
__launch_bounds__(256, 4)
__global__ void gemm_wh3_kernel(const bf16* __restrict__ A, const bf16* __restrict__ Bp,
                                const float* __restrict__ bias, bf16* __restrict__ C) {
  const int lane = threadIdx.x & 63;
  const int w = threadIdx.x >> 6;
  const int rowgrp = w & 1, nth = w >> 1;
  const int r0 = blockIdx.x * 32 + rowgrp * 16;
  int arow = r0 + (lane & 15);
  if (arow >= N_NODES) arow = N_NODES - 1;
  const int kb = (lane >> 4) << 3;
  short8 af[4];
#pragma unroll
  for (int kt = 0; kt < 4; ++kt)
    af[kt] = *(const short8*)(A + (size_t)arow * 128 + kt * 32 + kb);
  const int crow0 = r0 + ((lane >> 4) << 2);
  const int ccol = lane & 15;
  for (int e = 0; e < 3; ++e) {
    const bf16* Bpe = Bp + (size_t)e * 16384;
    const float* be = bias + e * 128;
    bf16* Ce = C + (size_t)e * N_NODES * 128;
#pragma unroll
    for (int q = 0; q < 4; ++q) {
      const int nt = nth * 4 + q;
      f32x4 acc = {0.f, 0.f, 0.f, 0.f};
#pragma unroll
      for (int kt = 0; kt < 4; ++kt) {
        short8 bfr = *(const short8*)(Bpe + ((kt * 8 + nt) * 64 + lane) * 8);
        acc = __builtin_amdgcn_mfma_f32_16x16x32_bf16(af[kt], bfr, acc, 0, 0, 0);
      }
      float bv = be[nt * 16 + ccol];
#pragma unroll
      for (int rr = 0; rr < 4; ++rr) {
        int row = crow0 + rr;
        if (row < N_NODES) Ce[(size_t)row * 128 + nt * 16 + ccol] = __float2bfloat16(acc[rr] + bv);
      }
    }
  }
}

// one wave per dst: lane-preloaded edge list + shfl broadcast, 2-way unrolled gather
__launch_bounds__(256)
__global__ void edge_gather_kernel(const int* __restrict__ off, const int* __restrict__ val,
                                   const bf16* __restrict__ Wh3, bf16* __restrict__ a) {
  int d = blockIdx.x * 4 + (threadIdx.x >> 6);
  if (d >= N_NODES) return;
  int lane = threadIdx.x & 63;
  int e0 = off[d];
  int deg = off[d + 1] - e0;
  float a0 = 0.f, a1 = 0.f, b0 = 0.f, b1 = 0.f;
  for (int base = 0; base < deg; base += 64) {
    int rem = deg - base; if (rem > 64) rem = 64;
    int v = (lane < rem) ? val[e0 + base + lane] : 0;
    int j = 0;
    for (; j + 2 <= rem; j += 2) {
      int v0 = __shfl(v, j), v1 = __shfl(v, j + 1);
      unsigned u0 = *(const unsigned*)(Wh3 +
                      ((size_t)(v0 >> 16) * N_NODES + (v0 & 0xFFFF)) * 128 + lane * 2);
      unsigned u1 = *(const unsigned*)(Wh3 +
                      ((size_t)(v1 >> 16) * N_NODES + (v1 & 0xFFFF)) * 128 + lane * 2);
      a0 += bfu((unsigned short)(u0 & 0xffff)); a1 += bfu((unsigned short)(u0 >> 16));
      b0 += bfu((unsigned short)(u1 & 0xffff)); b1 += bfu((unsigned short)(u1 >> 16));
    }
    if (j < rem) {
      int v0 = __shfl(v, j);
      unsigned u0 = *(const unsigned*)(Wh3 +
                      ((size_t)(v0 >> 16) * N_NODES + (v0 & 0xFFFF)) * 128 + lane * 2);
      a0 += bfu((unsigned short)(u0 & 0xffff)); a1 += bfu((unsigned short)(u0 >> 16));
    }
  }
  a0 += b0; a1 += b1;
  unsigned o = ((unsigned)(unsigned short)bfbits(a1) << 16) | (unsigned short)bfbits(a0);
  *(unsigned*)(a + (size_t)d * 128 + lane * 2) = o;
}

// ---------- fallback small-ws path ----------
__launch_bounds__(256)
__global__ void gemm_wh1_kernel(const bf16* __restrict__ A, const bf16* __restrict__ Bp,
                                const float* __restrict__ bias, bf16* __restrict__ C) {
  const int lane = threadIdx.x & 63;
  const int w = threadIdx.x >> 6;
  const int r0 = blockIdx.x * 64 + w * 16;
  int arow = r0 + (lane & 15);
  if (arow >= N_NODES) arow = N_NODES - 1;
  const int kb = (lane >> 4) << 3;
  short8 af[4];
#pragma unroll
  for (int kt = 0; kt < 4; ++kt)
    af[kt] = *(const short8*)(A + (size_t)arow * 128 + kt * 32 + kb);
  const int crow0 = r0 + ((lane >> 4) << 2);
  const int ccol = lane & 15;
#pragma unroll
  for (int nt = 0; nt < 8; ++nt) {
    f32x4 acc = {0.f, 0.f, 0.f, 0.f};
#pragma unroll
    for (int kt = 0; kt < 4; ++kt) {
      short8 bfr = *(const short8*)(Bp + ((kt * 8 + nt) * 64 + lane) * 8);
      acc = __builtin_amdgcn_mfma_f32_16x16x32_bf16(af[kt], bfr, acc, 0, 0, 0);
    }
    float bv = bias[nt * 16 + ccol];
#pragma unroll
    for (int rr = 0; rr < 4; ++rr) {
      int row = crow0 + rr;
      if (row < N_NODES) C[(size_t)row * 128 + nt * 16 + ccol] = __float2bfloat16(acc[rr] + bv);
    }
  }
}
__global__ void edge_kernel(const int* __restrict__ src, const int* __restrict__ dst,
                            const int* __restrict__ et, const bf16* __restrict__ Wh,
                            float* __restrict__ a, int pass) {
  int e = blockIdx.x * 4 + (threadIdx.x >> 6);
  if (et[e] != pass) return;
  int lane = threadIdx.x & 63;
  int s = src[e], d = dst[e];
  unsigned u = *(const unsigned*)(Wh + (size_t)s * 128 + lane * 2);
  atomicAdd(&a[(size_t)d * 128 + lane * 2],     bfu((unsigned short)(u & 0xffff)));
  atomicAdd(&a[(size_t)d * 128 + lane * 2 + 1], bfu((unsigned short)(u >> 16)));
}
__global__ void cvt_a_kernel(const float* __restrict__ af, bf16* __restrict__ ab) {
  int i = blockIdx.x * 256 + threadIdx.x;  // 6.4M
  ab[i] = __float2bfloat16(af[i]);
}
// ----------------------------------------------------------

// Fused GRU, nt split across waves: wave = (rowgrp, nthalf), 16 rows x 4 nt. grid 1563.
__launch_bounds__(256, 4)
__global__ void gru_kernel(const bf16* __restrict__ a, bf16* __restrict__ feat,
                           const bf16* __restrict__ Bih, const bf16* __restrict__ Bhh,
                           const float* __restrict__ bih, const float* __restrict__ bhh) {
  const int lane = threadIdx.x & 63;
  const int w = threadIdx.x >> 6;
  const int rowgrp = w & 1, nth = w >> 1;
  const int r0 = blockIdx.x * 32 + rowgrp * 16;
  int arow = r0 + (lane & 15);
  if (arow >= N_NODES) arow = N_NODES - 1;
  const int kb = (lane >> 4) << 3;
  short8 fa[4], fh[4];
#pragma unroll
  for (int kt = 0; kt < 4; ++kt) {
    fa[kt] = *(const short8*)(a + (size_t)arow * 128 + kt * 32 + kb);
    fh[kt] = *(const short8*)(feat + (size_t)arow * 128 + kt * 32 + kb);
  }
  const int crow0 = r0 + ((lane >> 4) << 2);
  const int ccol = lane & 15;
#pragma unroll
  for (int q = 0; q < 4; ++q) {
    const int nt = nth * 4 + q;
    f32x4 gi[3], gh[3];
#pragma unroll
    for (int g = 0; g < 3; ++g) { gi[g] = {0.f, 0.f, 0.f, 0.f}; gh[g] = {0.f, 0.f, 0.f, 0.f}; }
#pragma unroll
    for (int g = 0; g < 3; ++g) {
      const int ntg = g * 8 + nt;
#pragma unroll
      for (int kt = 0; kt < 4; ++kt) {
        short8 bi = *(const short8*)(Bih + ((size_t)(kt * 24 + ntg) * 64 + lane) * 8);
        short8 bh = *(const short8*)(Bhh + ((size_t)(kt * 24 + ntg) * 64 + lane) * 8);
        gi[g] = __builtin_amdgcn_mfma_f32_16x16x32_bf16(fa[kt], bi, gi[g], 0, 0, 0);
        gh[g] = __builtin_amdgcn_mfma_f32_16x16x32_bf16(fh[kt], bh, gh[g], 0, 0, 0);
      }
    }
    float bvi0 = bih[(0 * 8 + nt) * 16 + ccol], bvh0 = bhh[(0 * 8 + nt) * 16 + ccol];
    float bvi1 = bih[(1 * 8 + nt) * 16 + ccol], bvh1 = bhh[(1 * 8 + nt) * 16 + ccol];
    float bvi2 = bih[(2 * 8 + nt) * 16 + ccol], bvh2 = bhh[(2 * 8 + nt) * 16 + ccol];
#pragma unroll
    for (int rr = 0; rr < 4; ++rr) {
      int row = crow0 + rr;
      if (row < N_NODES) {
        int col = nt * 16 + ccol;
        float rg = 1.f / (1.f + __expf(-(gi[0][rr] + bvi0 + gh[0][rr] + bvh0)));
        float zg = 1.f / (1.f + __expf(-(gi[1][rr] + bvi1 + gh[1][rr] + bvh1)));
        float hn = gh[2][rr] + bvh2;
        float nc = tanhf(gi[2][rr] + bvi2 + rg * hn);
        float hv = __bfloat162float(feat[(size_t)row * 128 + col]);
        feat[(size_t)row * 128 + col] = __float2bfloat16((1.f - zg) * nc + zg * hv);
      }
    }
  }
}

// OUTPUT IS FLOAT32 (reference returns jax f32 arrays).
__global__ void final_kernel(const float* __restrict__ gsum, const float* __restrict__ cnt,
                             const float* __restrict__ W1, const float* __restrict__ b1,
                             const float* __restrict__ W2, const float* __restrict__ b2,
                             float* __restrict__ out) {
  __shared__ float ga[384];
  __shared__ float red[2];
  int g = blockIdx.x, t = threadIdx.x;
  float c = fmaxf(cnt[g], 1.f);
  for (int k = t; k < 384; k += 128) {
    float m = gsum[g * 384 + k] / c;
    ga[k] = m;
    out[64 + g * 384 + k] = m;
  }
  __syncthreads();
  float acc = b1[t];
  for (int k = 0; k < 384; ++k) acc += ga[k] * W1[k * 128 + t];
  float x = fmaxf(acc, 0.f);
  float pv = x * W2[t];
#pragma unroll
  for (int off = 32; off > 0; off >>= 1) pv += __shfl_down(pv, off);
  if ((t & 63) == 0) red[t >> 6] = pv;
  __syncthreads();
  if (t == 0) out[g] = red[0] + red[1] + b2[0];
}

extern "C" void kernel_launch(void* const* d_in, const int* in_sizes, int n_in,
                              void* d_out, int out_size, void* d_ws, size_t ws_size,
                              hipStream_t stream) {
  const int* text_idx = (const int*)d_in[0];
  const int* srcp     = (const int*)d_in[1];
  const int* dstp     = (const int*)d_in[2];
  const int* etype    = (const int*)d_in[3];
  const int* gid      = (const int*)d_in[4];
  float* out = (float*)d_out;
  float* ws = (float*)d_ws;

  const bool big = ws_size >= (size_t)82000000;

  bf16 *feat, *abf, *Wh, *packWe;
  float *af32 = nullptr, *canon, *gsum;
  int *csr_off = nullptr, *csr_cur = nullptr, *csr_deg = nullptr, *csr_val = nullptr,
      *csr_csums = nullptr, *csr_cbase = nullptr;
  if (big) {
    feat   = (bf16*)ws;
    abf    = (bf16*)(ws + 3200000);
    Wh     = (bf16*)(ws + 6400000);
    packWe = (bf16*)(ws + 16000000);
    canon  = ws + 16147456;
    gsum   = ws + 16494096;
    csr_off   = (int*)(ws + 16518744);
    csr_cur   = csr_off + 50001;
    csr_deg   = csr_cur + 50001;
    csr_val   = csr_deg + 50000;
    csr_csums = csr_val + 600000;
    csr_cbase = csr_csums + 256;
  } else {
    feat   = (bf16*)ws;
    af32   = ws + 3200000;
    Wh     = (bf16*)(ws + 9600000);
    packWe = (bf16*)(ws + 12800000);
    canon  = ws + 12947456;
    gsum   = ws + 13294096;
    abf    = Wh;
  }
  bf16* packWih = packWe + 98304;
  bf16* packWhh = packWih + 98304;
  float* cWl  = canon;
  float* cWih = canon + 98304;
  float* cWhh = canon + 196608;
  float* cbl  = canon + 294912;
  float* cbih = canon + 295680;
  float* cbhh = canon + 296448;
  float* cW1  = canon + 297216;
  float* cb1  = canon + 346368;
  float* cW2  = canon + 346496;
  float* cb2  = canon + 346624;
  float* cnt  = gsum + 24576;
  int*   fflag = (int*)(cnt + 64);

  detect_f_kernel<<<1, 64, 0, stream>>>((const unsigned short*)d_in[5], fflag);

  CvtArgs ca;
  ca.p[0] = d_in[6];  ca.p[1] = d_in[8];  ca.p[2] = d_in[9];  ca.p[3] = d_in[7];
  ca.p[4] = d_in[10]; ca.p[5] = d_in[11]; ca.p[6] = d_in[12]; ca.p[7] = d_in[13];
  ca.p[8] = d_in[14]; ca.p[9] = d_in[15];
  cvt_all_kernel<<<1355, 256, 0, stream>>>(ca, canon, fflag);

  hipMemsetAsync(gsum, 0, 24576 * sizeof(float), stream);
  pack_all_kernel<<<1152, 256, 0, stream>>>(cWl, cWih, cWhh, packWe, packWih, packWhh);

  if (big) {
    hipMemsetAsync(csr_deg, 0, 50000 * sizeof(int), stream);
    hist_kernel<<<2344, 256, 0, stream>>>(dstp, csr_deg);
    csr_chunk_sum<<<256, 256, 0, stream>>>(csr_deg, csr_csums);
    csr_bases<<<1, 64, 0, stream>>>(csr_csums, csr_cbase, csr_off);
    csr_write<<<256, 256, 0, stream>>>(csr_deg, csr_cbase, csr_off, csr_cur);
    scatter_kernel<<<2344, 256, 0, stream>>>(srcp, dstp, etype, csr_cur, csr_val);
  }

  embed_v8_kernel<<<3125, 256, 0, stream>>>(text_idx, d_in[5], feat, fflag);
  count_bs_kernel<<<1, 64, 0, stream>>>(gid, cnt);
  mean_sum_kernel<<<782, 256, 0, stream>>>(feat, gid, gsum, 0);

  for (int l = 0; l < 2; ++l) {
    for (int s = 0; s < 2; ++s) {
      if (big) {
        gemm_wh3_kernel<<<1563, 256, 0, stream>>>(feat, packWe + l * 3 * 16384,
                                                  cbl + l * 384, Wh);
        edge_gather_kernel<<<12500, 256, 0, stream>>>(csr_off, csr_val, Wh, abf);
      } else {
        hipMemsetAsync(af32, 0, 6400000 * sizeof(float), stream);
        for (int t = 0; t < 3; ++t) {
          gemm_wh1_kernel<<<782, 256, 0, stream>>>(feat, packWe + (l * 3 + t) * 16384,
                                                   cbl + l * 384 + t * 128, Wh);
          edge_kernel<<<150000, 256, 0, stream>>>(srcp, dstp, etype, Wh, af32, t);
        }
        cvt_a_kernel<<<25000, 256, 0, stream>>>(af32, abf);
      }
      gru_kernel<<<1563, 256, 0, stream>>>(abf, feat, packWih + l * 49152, packWhh + l * 49152,
                                           cbih + l * 384, cbhh + l * 384);
    }
    mean_sum_kernel<<<782, 256, 0, stream>>>(feat, gid, gsum, l + 1);
  }

  final_kernel<<<64, 128, 0, stream>>>(gsum, cnt, cW1, cb1, cW2, cb2, out);
}

// Round 15
// 528.307 us; speedup vs baseline: 5.9357x; 1.0302x over previous
//
#include <hip/hip_runtime.h>
#include <hip/hip_bf16.h>

#define N_NODES 50000
#define N_EDGES 600000
#define N_GRAPHS 64
#define CHUNK 196  // 256*196 >= 50000

typedef __hip_bfloat16 bf16;
typedef __attribute__((ext_vector_type(8))) short short8;
typedef __attribute__((ext_vector_type(4))) float f32x4;

static __device__ inline short bfbits(float x) {
  union { bf16 h; short s; } u;
  u.h = __float2bfloat16(x);
  return u.s;
}
static __device__ inline float bfu(unsigned short s) {
  union { float f; unsigned u; } x; x.u = ((unsigned)s) << 16; return x.f;
}
static __device__ inline short8 cvt8(const float* p) {
  f32x4 v0 = *(const f32x4*)p, v1 = *(const f32x4*)(p + 4);
  short8 r;
  r[0] = bfbits(v0[0]); r[1] = bfbits(v0[1]); r[2] = bfbits(v0[2]); r[3] = bfbits(v0[3]);
  r[4] = bfbits(v1[0]); r[5] = bfbits(v1[1]); r[6] = bfbits(v1[2]); r[7] = bfbits(v1[3]);
  return r;
}

// float dtype detection: bf16 (flag=0) or float32 (flag=1)?  (R5 verified: f32)
__global__ void detect_f_kernel(const unsigned short* __restrict__ raw, int* __restrict__ flag) {
  int t = threadIdx.x;  // 64
  int wild = 0;
  for (int i = 0; i < 4; ++i) {
    unsigned short u = raw[t * 4 + i];
    int e = (u >> 7) & 0xFF;
    if (u != 0 && (e < 96 || e > 159)) wild++;
  }
#pragma unroll
  for (int off = 32; off > 0; off >>= 1) wild += __shfl_down(wild, off);
  if (t == 0) *flag = (wild >= 32) ? 1 : 0;
}

// all 10 small float params -> canon, one launch
struct CvtArgs { const void* p[10]; };
__global__ void cvt_all_kernel(CvtArgs args, float* __restrict__ canon,
                               const int* __restrict__ flag) {
  int i = blockIdx.x * 256 + threadIdx.x;
  if (i >= 346625) return;
  const int offs[11] = {0, 98304, 196608, 294912, 295680, 296448,
                        297216, 346368, 346496, 346624, 346625};
  int seg = 0;
#pragma unroll
  for (int k = 1; k < 10; ++k) if (i >= offs[k]) seg = k;
  int j = i - offs[seg];
  const void* s = args.p[seg];
  canon[i] = (*flag) ? ((const float*)s)[j] : bfu(((const unsigned short*)s)[j]);
}

// all weight packs in one launch (294,912 elements)
__global__ void pack_all_kernel(const float* __restrict__ cWl, const float* __restrict__ cWih,
                                const float* __restrict__ cWhh, bf16* __restrict__ packWe,
                                bf16* __restrict__ packWih, bf16* __restrict__ packWhh) {
  int tid = blockIdx.x * 256 + threadIdx.x;
  if (tid >= 294912) return;
  const float* src; bf16* dst; int NN, transpose, within;
  if (tid < 98304) {
    int m = tid >> 14; within = tid & 16383;
    src = cWl + m * 16384; dst = packWe + m * 16384; NN = 128; transpose = 0;
  } else if (tid < 196608) {
    int t2 = tid - 98304; int l = t2 / 49152; within = t2 % 49152;
    src = cWih + l * 49152; dst = packWih + l * 49152; NN = 384; transpose = 1;
  } else {
    int t2 = tid - 196608; int l = t2 / 49152; within = t2 % 49152;
    src = cWhh + l * 49152; dst = packWhh + l * 49152; NN = 384; transpose = 1;
  }
  int NT = NN >> 4;
  int i = within & 7;
  int lane = (within >> 3) & 63;
  int rest = within >> 9;
  int nt = rest % NT, kt = rest / NT;
  int k = kt * 32 + ((lane >> 4) << 3) + i;
  int n = nt * 16 + (lane & 15);
  dst[within] = __float2bfloat16(transpose ? src[n * 128 + k] : src[k * NN + n]);
}

__global__ void embed_v8_kernel(const int* __restrict__ idx, const void* __restrict__ emb_raw,
                                bf16* __restrict__ feat, const int* __restrict__ flag) {
  int tid = blockIdx.x * 256 + threadIdx.x;  // 800,000 exactly
  int n = tid >> 4, q = tid & 15;
  short8 o;
  if (*flag) {
    o = cvt8((const float*)emb_raw + (size_t)idx[n] * 128 + q * 8);
  } else {
    o = *(const short8*)((const unsigned short*)emb_raw + (size_t)idx[n] * 128 + q * 8);
  }
  *(short8*)(feat + (size_t)tid * 8) = o;
}

__global__ void count_bs_kernel(const int* __restrict__ gid, float* __restrict__ cnt) {
  int g = threadIdx.x;  // 0..63
  int lo = 0, hi = N_NODES;
  while (lo < hi) { int m = (lo + hi) >> 1; if (gid[m] < g) lo = m + 1; else hi = m; }
  int a0 = lo; hi = N_NODES;
  while (lo < hi) { int m = (lo + hi) >> 1; if (gid[m] < g + 1) lo = m + 1; else hi = m; }
  cnt[g] = (float)(lo - a0);
}

__global__ void mean_sum_kernel(const bf16* __restrict__ feat, const int* __restrict__ gid,
                                float* __restrict__ gsum, int slot) {
  int n0 = blockIdx.x * 64;        // grid 782
  int h = threadIdx.x & 127;
  int r = threadIdx.x >> 7;
  float acc = 0.f; int curg = -1;
  for (int nn = r; nn < 64; nn += 2) {
    int node = n0 + nn;
    if (node >= N_NODES) break;
    int g = gid[node];
    if (g != curg) {
      if (curg >= 0) atomicAdd(&gsum[curg * 384 + slot * 128 + h], acc);
      curg = g; acc = 0.f;
    }
    acc += __bfloat162float(feat[(size_t)node * 128 + h]);
  }
  if (curg >= 0) atomicAdd(&gsum[curg * 384 + slot * 128 + h], acc);
}

// ---------- CSR build (parallel scan) ----------
__global__ void hist_kernel(const int* __restrict__ dst, int* __restrict__ deg) {
  int e = blockIdx.x * 256 + threadIdx.x;
  if (e < N_EDGES) atomicAdd(&deg[dst[e]], 1);
}
__global__ void csr_chunk_sum(const int* __restrict__ deg, int* __restrict__ csums) {
  __shared__ int sm[256];
  int b = blockIdx.x, t = threadIdx.x;
  int i = b * CHUNK + t;
  sm[t] = (t < CHUNK && i < N_NODES) ? deg[i] : 0;
  __syncthreads();
  for (int s = 128; s > 0; s >>= 1) { if (t < s) sm[t] += sm[t + s]; __syncthreads(); }
  if (t == 0) csums[b] = sm[0];
}
__global__ void csr_bases(const int* __restrict__ csums, int* __restrict__ cbase,
                          int* __restrict__ off) {
  int lane = threadIdx.x;  // 64
  int s0 = csums[lane * 4], s1 = csums[lane * 4 + 1];
  int s2 = csums[lane * 4 + 2], s3 = csums[lane * 4 + 3];
  int tot = s0 + s1 + s2 + s3;
  int sc = tot;
  for (int o = 1; o < 64; o <<= 1) { int u = __shfl_up(sc, o); if (lane >= o) sc += u; }
  int base = sc - tot;
  cbase[lane * 4] = base;
  cbase[lane * 4 + 1] = base + s0;
  cbase[lane * 4 + 2] = base + s0 + s1;
  cbase[lane * 4 + 3] = base + s0 + s1 + s2;
  if (lane == 63) off[N_NODES] = base + tot;
}
__global__ void csr_write(const int* __restrict__ deg, const int* __restrict__ cbase,
                          int* __restrict__ off, int* __restrict__ cur) {
  __shared__ int A[256], B[256];
  int b = blockIdx.x, t = threadIdx.x;
  int i = b * CHUNK + t;
  int d = (t < CHUNK && i < N_NODES) ? deg[i] : 0;
  A[t] = d; __syncthreads();
  int* in = A; int* out = B;
  for (int s = 1; s < 256; s <<= 1) {
    out[t] = in[t] + ((t >= s) ? in[t - s] : 0);
    __syncthreads();
    int* tmp = in; in = out; out = tmp;
  }
  if (t < CHUNK && i < N_NODES) {
    int o = cbase[b] + in[t] - d;
    off[i] = o; cur[i] = o;
  }
}
__global__ void scatter_kernel(const int* __restrict__ src, const int* __restrict__ dst,
                               const int* __restrict__ et, int* __restrict__ cur,
                               int* __restrict__ val) {
  int e = blockIdx.x * 256 + threadIdx.x;
  if (e >= N_EDGES) return;
  int pos = atomicAdd(&cur[dst[e]], 1);
  val[pos] = src[e] | (et[e] << 16);
}

// Wh3: wave = nth (0..3) covering nt = nth*2 + q; 32 rows (2 rowgroups) per block.
// B loaded once per (e,q,kt), feeds 2 MFMAs. grid 1563.
__launch_bounds__(256, 4)
__global__ void gemm_wh3_kernel(const bf16* __restrict__ A, const bf16* __restrict__ Bp,
                                const float* __restrict__ bias, bf16* __restrict__ C) {
  const int lane = threadIdx.x & 63;
  const int nth = threadIdx.x >> 6;
  const int r0 = blockIdx.x * 32;
  const int kb = (lane >> 4) << 3;
  short8 af[2][4];
#pragma unroll
  for (int rg = 0; rg < 2; ++rg) {
    int arow = r0 + rg * 16 + (lane & 15);
    if (arow >= N_NODES) arow = N_NODES - 1;
#pragma unroll
    for (int kt = 0; kt < 4; ++kt)
      af[rg][kt] = *(const short8*)(A + (size_t)arow * 128 + kt * 32 + kb);
  }
  const int crow0 = r0 + ((lane >> 4) << 2);
  const int ccol = lane & 15;
  for (int e = 0; e < 3; ++e) {
    const bf16* Bpe = Bp + (size_t)e * 16384;
    const float* be = bias + e * 128;
    bf16* Ce = C + (size_t)e * N_NODES * 128;
#pragma unroll
    for (int q = 0; q < 2; ++q) {
      const int nt = nth * 2 + q;
      f32x4 acc0 = {0.f, 0.f, 0.f, 0.f}, acc1 = {0.f, 0.f, 0.f, 0.f};
#pragma unroll
      for (int kt = 0; kt < 4; ++kt) {
        short8 bfr = *(const short8*)(Bpe + ((kt * 8 + nt) * 64 + lane) * 8);
        acc0 = __builtin_amdgcn_mfma_f32_16x16x32_bf16(af[0][kt], bfr, acc0, 0, 0, 0);
        acc1 = __builtin_amdgcn_mfma_f32_16x16x32_bf16(af[1][kt], bfr, acc1, 0, 0, 0);
      }
      float bv = be[nt * 16 + ccol];
#pragma unroll
      for (int rr = 0; rr < 4; ++rr) {
        int row0 = crow0 + rr;
        if (row0 < N_NODES)
          Ce[(size_t)row0 * 128 + nt * 16 + ccol] = __float2bfloat16(acc0[rr] + bv);
        int row1 = crow0 + 16 + rr;
        if (row1 < N_NODES)
          Ce[(size_t)row1 * 128 + nt * 16 + ccol] = __float2bfloat16(acc1[rr] + bv);
      }
    }
  }
}

// one wave per dst: lane-preloaded edge list + shfl broadcast, 2-way unrolled gather
__launch_bounds__(256)
__global__ void edge_gather_kernel(const int* __restrict__ off, const int* __restrict__ val,
                                   const bf16* __restrict__ Wh3, bf16* __restrict__ a) {
  int d = blockIdx.x * 4 + (threadIdx.x >> 6);
  if (d >= N_NODES) return;
  int lane = threadIdx.x & 63;
  int e0 = off[d];
  int deg = off[d + 1] - e0;
  float a0 = 0.f, a1 = 0.f, b0 = 0.f, b1 = 0.f;
  for (int base = 0; base < deg; base += 64) {
    int rem = deg - base; if (rem > 64) rem = 64;
    int v = (lane < rem) ? val[e0 + base + lane] : 0;
    int j = 0;
    for (; j + 2 <= rem; j += 2) {
      int v0 = __shfl(v, j), v1 = __shfl(v, j + 1);
      unsigned u0 = *(const unsigned*)(Wh3 +
                      ((size_t)(v0 >> 16) * N_NODES + (v0 & 0xFFFF)) * 128 + lane * 2);
      unsigned u1 = *(const unsigned*)(Wh3 +
                      ((size_t)(v1 >> 16) * N_NODES + (v1 & 0xFFFF)) * 128 + lane * 2);
      a0 += bfu((unsigned short)(u0 & 0xffff)); a1 += bfu((unsigned short)(u0 >> 16));
      b0 += bfu((unsigned short)(u1 & 0xffff)); b1 += bfu((unsigned short)(u1 >> 16));
    }
    if (j < rem) {
      int v0 = __shfl(v, j);
      unsigned u0 = *(const unsigned*)(Wh3 +
                      ((size_t)(v0 >> 16) * N_NODES + (v0 & 0xFFFF)) * 128 + lane * 2);
      a0 += bfu((unsigned short)(u0 & 0xffff)); a1 += bfu((unsigned short)(u0 >> 16));
    }
  }
  a0 += b0; a1 += b1;
  unsigned o = ((unsigned)(unsigned short)bfbits(a1) << 16) | (unsigned short)bfbits(a0);
  *(unsigned*)(a + (size_t)d * 128 + lane * 2) = o;
}

// ---------- fallback small-ws path ----------
__launch_bounds__(256)
__global__ void gemm_wh1_kernel(const bf16* __restrict__ A, const bf16* __restrict__ Bp,
                                const float* __restrict__ bias, bf16* __restrict__ C) {
  const int lane = threadIdx.x & 63;
  const int w = threadIdx.x >> 6;
  const int r0 = blockIdx.x * 64 + w * 16;
  int arow = r0 + (lane & 15);
  if (arow >= N_NODES) arow = N_NODES - 1;
  const int kb = (lane >> 4) << 3;
  short8 af[4];
#pragma unroll
  for (int kt = 0; kt < 4; ++kt)
    af[kt] = *(const short8*)(A + (size_t)arow * 128 + kt * 32 + kb);
  const int crow0 = r0 + ((lane >> 4) << 2);
  const int ccol = lane & 15;
#pragma unroll
  for (int nt = 0; nt < 8; ++nt) {
    f32x4 acc = {0.f, 0.f, 0.f, 0.f};
#pragma unroll
    for (int kt = 0; kt < 4; ++kt) {
      short8 bfr = *(const short8*)(Bp + ((kt * 8 + nt) * 64 + lane) * 8);
      acc = __builtin_amdgcn_mfma_f32_16x16x32_bf16(af[kt], bfr, acc, 0, 0, 0);
    }
    float bv = bias[nt * 16 + ccol];
#pragma unroll
    for (int rr = 0; rr < 4; ++rr) {
      int row = crow0 + rr;
      if (row < N_NODES) C[(size_t)row * 128 + nt * 16 + ccol] = __float2bfloat16(acc[rr] + bv);
    }
  }
}
__global__ void edge_kernel(const int* __restrict__ src, const int* __restrict__ dst,
                            const int* __restrict__ et, const bf16* __restrict__ Wh,
                            float* __restrict__ a, int pass) {
  int e = blockIdx.x * 4 + (threadIdx.x >> 6);
  if (et[e] != pass) return;
  int lane = threadIdx.x & 63;
  int s = src[e], d = dst[e];
  unsigned u = *(const unsigned*)(Wh + (size_t)s * 128 + lane * 2);
  atomicAdd(&a[(size_t)d * 128 + lane * 2],     bfu((unsigned short)(u & 0xffff)));
  atomicAdd(&a[(size_t)d * 128 + lane * 2 + 1], bfu((unsigned short)(u >> 16)));
}
__global__ void cvt_a_kernel(const float* __restrict__ af, bf16* __restrict__ ab) {
  int i = blockIdx.x * 256 + threadIdx.x;  // 6.4M
  ab[i] = __float2bfloat16(af[i]);
}
// ----------------------------------------------------------

// Fused GRU: wave = nth (0..3), nt = nth*2+q; 32 rows (2 rowgroups) per block.
// B loaded once per (g,q,kt), feeds 2 MFMAs for gi and 2 for gh. grid 1563.
__launch_bounds__(256, 3)
__global__ void gru_kernel(const bf16* __restrict__ a, bf16* __restrict__ feat,
                           const bf16* __restrict__ Bih, const bf16* __restrict__ Bhh,
                           const float* __restrict__ bih, const float* __restrict__ bhh) {
  const int lane = threadIdx.x & 63;
  const int nth = threadIdx.x >> 6;
  const int r0 = blockIdx.x * 32;
  const int kb = (lane >> 4) << 3;
  short8 fa[2][4], fh[2][4];
#pragma unroll
  for (int rg = 0; rg < 2; ++rg) {
    int arow = r0 + rg * 16 + (lane & 15);
    if (arow >= N_NODES) arow = N_NODES - 1;
#pragma unroll
    for (int kt = 0; kt < 4; ++kt) {
      fa[rg][kt] = *(const short8*)(a + (size_t)arow * 128 + kt * 32 + kb);
      fh[rg][kt] = *(const short8*)(feat + (size_t)arow * 128 + kt * 32 + kb);
    }
  }
  const int crow0 = r0 + ((lane >> 4) << 2);
  const int ccol = lane & 15;
#pragma unroll
  for (int q = 0; q < 2; ++q) {
    const int nt = nth * 2 + q;
    f32x4 gi[3][2], gh[3][2];
#pragma unroll
    for (int g = 0; g < 3; ++g)
#pragma unroll
      for (int rg = 0; rg < 2; ++rg) {
        gi[g][rg] = {0.f, 0.f, 0.f, 0.f};
        gh[g][rg] = {0.f, 0.f, 0.f, 0.f};
      }
#pragma unroll
    for (int g = 0; g < 3; ++g) {
      const int ntg = g * 8 + nt;
#pragma unroll
      for (int kt = 0; kt < 4; ++kt) {
        short8 bi = *(const short8*)(Bih + ((size_t)(kt * 24 + ntg) * 64 + lane) * 8);
        short8 bh = *(const short8*)(Bhh + ((size_t)(kt * 24 + ntg) * 64 + lane) * 8);
        gi[g][0] = __builtin_amdgcn_mfma_f32_16x16x32_bf16(fa[0][kt], bi, gi[g][0], 0, 0, 0);
        gi[g][1] = __builtin_amdgcn_mfma_f32_16x16x32_bf16(fa[1][kt], bi, gi[g][1], 0, 0, 0);
        gh[g][0] = __builtin_amdgcn_mfma_f32_16x16x32_bf16(fh[0][kt], bh, gh[g][0], 0, 0, 0);
        gh[g][1] = __builtin_amdgcn_mfma_f32_16x16x32_bf16(fh[1][kt], bh, gh[g][1], 0, 0, 0);
      }
    }
    float bvi0 = bih[(0 * 8 + nt) * 16 + ccol], bvh0 = bhh[(0 * 8 + nt) * 16 + ccol];
    float bvi1 = bih[(1 * 8 + nt) * 16 + ccol], bvh1 = bhh[(1 * 8 + nt) * 16 + ccol];
    float bvi2 = bih[(2 * 8 + nt) * 16 + ccol], bvh2 = bhh[(2 * 8 + nt) * 16 + ccol];
#pragma unroll
    for (int rg = 0; rg < 2; ++rg) {
#pragma unroll
      for (int rr = 0; rr < 4; ++rr) {
        int row = crow0 + rg * 16 + rr;
        if (row < N_NODES) {
          int col = nt * 16 + ccol;
          float rgate = 1.f / (1.f + __expf(-(gi[0][rg][rr] + bvi0 + gh[0][rg][rr] + bvh0)));
          float zgate = 1.f / (1.f + __expf(-(gi[1][rg][rr] + bvi1 + gh[1][rg][rr] + bvh1)));
          float x = gi[2][rg][rr] + bvi2 + rgate * (gh[2][rg][rr] + bvh2);
          float t = __expf(2.f * x);
          float nc = 1.f - 2.f / (t + 1.f);   // tanh(x)
          float hv = __bfloat162float(feat[(size_t)row * 128 + col]);
          feat[(size_t)row * 128 + col] = __float2bfloat16((1.f - zgate) * nc + zgate * hv);
        }
      }
    }
  }
}

// OUTPUT IS FLOAT32 (reference returns jax f32 arrays).
__global__ void final_kernel(const float* __restrict__ gsum, const float* __restrict__ cnt,
                             const float* __restrict__ W1, const float* __restrict__ b1,
                             const float* __restrict__ W2, const float* __restrict__ b2,
                             float* __restrict__ out) {
  __shared__ float ga[384];
  __shared__ float red[2];
  int g = blockIdx.x, t = threadIdx.x;
  float c = fmaxf(cnt[g], 1.f);
  for (int k = t; k < 384; k += 128) {
    float m = gsum[g * 384 + k] / c;
    ga[k] = m;
    out[64 + g * 384 + k] = m;
  }
  __syncthreads();
  float acc = b1[t];
  for (int k = 0; k < 384; ++k) acc += ga[k] * W1[k * 128 + t];
  float x = fmaxf(acc, 0.f);
  float pv = x * W2[t];
#pragma unroll
  for (int off = 32; off > 0; off >>= 1) pv += __shfl_down(pv, off);
  if ((t & 63) == 0) red[t >> 6] = pv;
  __syncthreads();
  if (t == 0) out[g] = red[0] + red[1] + b2[0];
}

extern "C" void kernel_launch(void* const* d_in, const int* in_sizes, int n_in,
                              void* d_out, int out_size, void* d_ws, size_t ws_size,
                              hipStream_t stream) {
  const int* text_idx = (const int*)d_in[0];
  const int* srcp     = (const int*)d_in[1];
  const int* dstp     = (const int*)d_in[2];
  const int* etype    = (const int*)d_in[3];
  const int* gid      = (const int*)d_in[4];
  float* out = (float*)d_out;
  float* ws = (float*)d_ws;

  const bool big = ws_size >= (size_t)82000000;

  bf16 *feat, *abf, *Wh, *packWe;
  float *af32 = nullptr, *canon, *gsum;
  int *csr_off = nullptr, *csr_cur = nullptr, *csr_deg = nullptr, *csr_val = nullptr,
      *csr_csums = nullptr, *csr_cbase = nullptr;
  if (big) {
    feat   = (bf16*)ws;
    abf    = (bf16*)(ws + 3200000);
    Wh     = (bf16*)(ws + 6400000);
    packWe = (bf16*)(ws + 16000000);
    canon  = ws + 16147456;
    gsum   = ws + 16494096;
    csr_off   = (int*)(ws + 16518744);
    csr_cur   = csr_off + 50001;
    csr_deg   = csr_cur + 50001;
    csr_val   = csr_deg + 50000;
    csr_csums = csr_val + 600000;
    csr_cbase = csr_csums + 256;
  } else {
    feat   = (bf16*)ws;
    af32   = ws + 3200000;
    Wh     = (bf16*)(ws + 9600000);
    packWe = (bf16*)(ws + 12800000);
    canon  = ws + 12947456;
    gsum   = ws + 13294096;
    abf    = Wh;
  }
  bf16* packWih = packWe + 98304;
  bf16* packWhh = packWih + 98304;
  float* cWl  = canon;
  float* cWih = canon + 98304;
  float* cWhh = canon + 196608;
  float* cbl  = canon + 294912;
  float* cbih = canon + 295680;
  float* cbhh = canon + 296448;
  float* cW1  = canon + 297216;
  float* cb1  = canon + 346368;
  float* cW2  = canon + 346496;
  float* cb2  = canon + 346624;
  float* cnt  = gsum + 24576;
  int*   fflag = (int*)(cnt + 64);

  detect_f_kernel<<<1, 64, 0, stream>>>((const unsigned short*)d_in[5], fflag);

  CvtArgs ca;
  ca.p[0] = d_in[6];  ca.p[1] = d_in[8];  ca.p[2] = d_in[9];  ca.p[3] = d_in[7];
  ca.p[4] = d_in[10]; ca.p[5] = d_in[11]; ca.p[6] = d_in[12]; ca.p[7] = d_in[13];
  ca.p[8] = d_in[14]; ca.p[9] = d_in[15];
  cvt_all_kernel<<<1355, 256, 0, stream>>>(ca, canon, fflag);

  hipMemsetAsync(gsum, 0, 24576 * sizeof(float), stream);
  pack_all_kernel<<<1152, 256, 0, stream>>>(cWl, cWih, cWhh, packWe, packWih, packWhh);

  if (big) {
    hipMemsetAsync(csr_deg, 0, 50000 * sizeof(int), stream);
    hist_kernel<<<2344, 256, 0, stream>>>(dstp, csr_deg);
    csr_chunk_sum<<<256, 256, 0, stream>>>(csr_deg, csr_csums);
    csr_bases<<<1, 64, 0, stream>>>(csr_csums, csr_cbase, csr_off);
    csr_write<<<256, 256, 0, stream>>>(csr_deg, csr_cbase, csr_off, csr_cur);
    scatter_kernel<<<2344, 256, 0, stream>>>(srcp, dstp, etype, csr_cur, csr_val);
  }

  embed_v8_kernel<<<3125, 256, 0, stream>>>(text_idx, d_in[5], feat, fflag);
  count_bs_kernel<<<1, 64, 0, stream>>>(gid, cnt);
  mean_sum_kernel<<<782, 256, 0, stream>>>(feat, gid, gsum, 0);

  for (int l = 0; l < 2; ++l) {
    for (int s = 0; s < 2; ++s) {
      if (big) {
        gemm_wh3_kernel<<<1563, 256, 0, stream>>>(feat, packWe + l * 3 * 16384,
                                                  cbl + l * 384, Wh);
        edge_gather_kernel<<<12500, 256, 0, stream>>>(csr_off, csr_val, Wh, abf);
      } else {
        hipMemsetAsync(af32, 0, 6400000 * sizeof(float), stream);
        for (int t = 0; t < 3; ++t) {
          gemm_wh1_kernel<<<782, 256, 0, stream>>>(feat, packWe + (l * 3 + t) * 16384,
                                                   cbl + l * 384 + t * 128, Wh);
          edge_kernel<<<150000, 256, 0, stream>>>(srcp, dstp, etype, Wh, af32, t);
        }
        cvt_a_kernel<<<25000, 256, 0, stream>>>(af32, abf);
      }
      gru_kernel<<<1563, 256, 0, stream>>>(abf, feat, packWih + l * 49152, packWhh + l * 49152,
                                           cbih + l * 384, cbhh + l * 384);
    }
    mean_sum_kernel<<<782, 256, 0, stream>>>(feat, gid, gsum, l + 1);
  }

  final_kernel<<<64, 128, 0, stream>>>(gsum, cnt, cW1, cb1, cW2, cb2, out);
}